// Round 6
// baseline (11801.325 us; speedup 1.0000x reference)
//
#include <hip/hip_runtime.h>
#include <math.h>

#define TT 512
#define NB 16

// ---------------- LDS byte offsets (backward) ----------------
#define QH_B   0        // QH  [96][100] f32 (col 96 = qh)
#define LI_B   38400    // LI  [32][36]  f32
#define T1_B   43008    // T1T [65][36]  f32  (row 64 = qu-solve)
#define VBH_B  52368    // Vbf-hi [64][72] us
#define VBL_B  61584    // Vbf-lo
#define FTH_B  70800    // FTbf-hi [96][72] us   FT[c][k] = F[k][c]
#define FTL_B  84624
#define WTH_B  98448    // WTbf-hi [96][72] us   WT[c][i] = W[i][c]
#define WTL_B  112272
#define VR_B   98448    // VRAW [64][72] f32 (aliases WT region, P6 only)
#define XUH_B  126096   // QXUbf-hi [64][40] us  XU[xrow][ucol]
#define XUL_B  131216
#define KTH_B  136336   // KTbf-hi [64][40] us   KT[c][j] = K[j][c]
#define KTL_B  141456
#define QHF_B  146576   // qhF [96] f32
#define VV_B   146960   // v [64] f32
#define CV_B   147216   // c [64] f32
#define KV_B   147472   // k [32] f32
#define SMB    147600

// ---------------- forward overlay (float offsets) ----------------
#define AB0 0
#define AB1 6400
#define KF0 12800
#define KF1 14976
#define XB0 17152
#define XB1 17216
#define UBO 17280
#define AXO 17312

#define WSK_STRIDE 2080   // per (b,t): rows j: [j*65 + c], col 64 = k

typedef __attribute__((ext_vector_type(8))) short s8v;
typedef __attribute__((ext_vector_type(4))) float f4v;

__device__ __forceinline__ float lanebc(float x, int lane) {
    return __int_as_float(__builtin_amdgcn_readlane(__float_as_int(x), lane));
}
__device__ __forceinline__ float dot4(float4 a, float4 b) {
    return a.x * b.x + a.y * b.y + a.z * b.z + a.w * b.w;
}
__device__ __forceinline__ unsigned short f2bf(float x) {
    unsigned int u = __float_as_uint(x);
    u += 0x7FFFu + ((u >> 16) & 1u);           // RNE
    return (unsigned short)(u >> 16);
}
__device__ __forceinline__ float bf2f(unsigned short h) {
    return __uint_as_float(((unsigned int)h) << 16);
}
// lower-triangular 16x16 tile enumeration: T=0..20 -> (mt,nt), nt<=mt
__device__ __forceinline__ void tileMN(int T, int& mt, int& nt) {
    mt = (T >= 15) ? 5 : (T >= 10) ? 4 : (T >= 6) ? 3 : (T >= 3) ? 2 : (T >= 1) ? 1 : 0;
    nt = T - mt * (mt + 1) / 2;
}
#define MFMA(a,b,c) __builtin_amdgcn_mfma_f32_16x16x32_bf16((a),(b),(c),0,0,0)

__launch_bounds__(1024, 1)
__global__ void lqr_kernel(const float* __restrict__ Q, const float* __restrict__ P,
                           const float* __restrict__ A, const float* __restrict__ B,
                           const float* __restrict__ c1, const float* __restrict__ xinit,
                           float* __restrict__ out, float* __restrict__ ws)
{
    __shared__ __align__(16) unsigned char smb[SMB];
    float*          QHf = (float*)(smb + QH_B);
    float*          LIf = (float*)(smb + LI_B);
    float*          T1f = (float*)(smb + T1_B);
    unsigned short* VBH = (unsigned short*)(smb + VBH_B);
    unsigned short* VBL = (unsigned short*)(smb + VBL_B);
    unsigned short* FTH = (unsigned short*)(smb + FTH_B);
    unsigned short* FTL = (unsigned short*)(smb + FTL_B);
    unsigned short* WTH = (unsigned short*)(smb + WTH_B);
    unsigned short* WTL = (unsigned short*)(smb + WTL_B);
    float*          VRW = (float*)(smb + VR_B);
    unsigned short* XUH = (unsigned short*)(smb + XUH_B);
    unsigned short* XUL = (unsigned short*)(smb + XUL_B);
    unsigned short* KTH = (unsigned short*)(smb + KTH_B);
    unsigned short* KTL = (unsigned short*)(smb + KTL_B);
    float*          QHF = (float*)(smb + QHF_B);
    float*          VVf = (float*)(smb + VV_B);
    float*          CVf = (float*)(smb + CV_B);
    float*          KVf = (float*)(smb + KV_B);

    const int tid = threadIdx.x;
    const int b   = blockIdx.x;
    const int wv  = tid >> 6;   // 0..15
    const int ln  = tid & 63;
    const int l15 = ln & 15;
    const int lq  = ln >> 4;
    float* wsK = ws;

    const int qcnt = (wv < 5) ? 2 : 1;      // Q lower tiles per wave: {wv, 16+wv}
    const int qr = ln >> 2, qc4 = ln & 3;   // Q-stage lane mapping

    // ---- prologue: issue Q loads for t=511 immediately ----
    float4 qreg[2];
    {
        const float* Qg = Q + ((size_t)b * TT + (TT - 1)) * 9216;
#pragma unroll
        for (int tt = 0; tt < 2; ++tt) if (tt < qcnt) {
            int T = wv + 16 * tt, mt, nt; tileMN(T, mt, nt);
            qreg[tt] = *(const float4*)&Qg[(16 * mt + qr) * 96 + 16 * nt + 4 * qc4];
        }
    }

    // ---------------- init: Vbf=0, v=0, stage FTbf for t=511 ----------------
    if (tid < 768) {
        const size_t bt = (size_t)b * TT + (TT - 1);
        const int kk = tid & 63, cq = tid >> 6;   // cq 0..11
#pragma unroll
        for (int q = 0; q < 2; ++q) {
            int col0 = 8 * cq + 4 * q;
            const float* src = (col0 < 64) ? (A + (bt * 64 + kk) * 64 + col0)
                                           : (B + (bt * 64 + kk) * 32 + col0 - 64);
            float4 v = *(const float4*)src;
#pragma unroll
            for (int e = 0; e < 4; ++e) {
                int col = col0 + e;
                float x = (e == 0) ? v.x : (e == 1) ? v.y : (e == 2) ? v.z : v.w;
                unsigned short h = f2bf(x);
                FTH[col * 72 + kk] = h;
                FTL[col * 72 + kk] = f2bf(x - bf2f(h));
            }
        }
    } else {
        float* vb = (float*)VBH;   // zero Vbf hi+lo (4608 floats contiguous)
        for (int i = tid - 768; i < 4608; i += 256) vb[i] = 0.0f;
        if (tid >= 768 && tid < 832) VVf[tid - 768] = 0.0f;
    }
    __syncthreads();

    // ================= backward Riccati recursion =================
    for (int t = TT - 1; t >= 0; --t) {
        const size_t bt  = (size_t)b * TT + t;
        const size_t btp = (size_t)b * TT + ((t > 0) ? (t - 1) : 0);

        // ---- P1-start: commit prefetched Q_t tiles; issue next Q; prefetch A/B ----
#pragma unroll
        for (int tt = 0; tt < 2; ++tt) if (tt < qcnt) {
            int T = wv + 16 * tt, mt, nt; tileMN(T, mt, nt);
            *(float4*)&QHf[(16 * mt + qr) * 100 + 16 * nt + 4 * qc4] = qreg[tt];
        }
        {
            const float* Qg = Q + btp * 9216;
#pragma unroll
            for (int tt = 0; tt < 2; ++tt) if (tt < qcnt) {
                int T = wv + 16 * tt, mt, nt; tileMN(T, mt, nt);
                qreg[tt] = *(const float4*)&Qg[(16 * mt + qr) * 96 + 16 * nt + 4 * qc4];
            }
        }
        float4 fp4[2];
        if (wv >= 1 && wv <= 12) {
            const int tau = tid - 64, kk = tau & 63, cq = tau >> 6;   // cq 0..11
#pragma unroll
            for (int q = 0; q < 2; ++q) {
                int col0 = 8 * cq + 4 * q;
                const float* src = (col0 < 64) ? (A + (btp * 64 + kk) * 64 + col0)
                                               : (B + (btp * 64 + kk) * 32 + col0 - 64);
                fp4[q] = *(const float4*)src;
            }
        }
        if (wv == 13 && ln < 16)
            *(float4*)&CVf[4 * ln] = *(const float4*)&c1[bt * 64 + 4 * ln];
        float pv = 0.0f;
        if (wv < 12 && (ln & 7) == 0) pv = P[bt * 96 + 8 * wv + (ln >> 3)];

        // ---- P1: GEMM1 (WT = (VF)^T via MFMA, 24 tiles) + qhF = p + F^T v ----
        {
            int t1l[2]; int nT1;
            if (wv < 8) { t1l[0] = 2 * wv; t1l[1] = 2 * wv + 1; nT1 = 2; }
            else        { t1l[0] = 8 + wv; t1l[1] = 0;          nT1 = 1; }
#pragma unroll
            for (int tt = 0; tt < 2; ++tt) if (tt < nT1) {
                int T = t1l[tt], mt = T >> 2, nt = T & 3;
                const unsigned short* ah = FTH + (16 * mt + l15) * 72 + 8 * lq;
                const unsigned short* al = FTL + (16 * mt + l15) * 72 + 8 * lq;
                const unsigned short* bh = VBH + (16 * nt + l15) * 72 + 8 * lq;
                const unsigned short* bl = VBL + (16 * nt + l15) * 72 + 8 * lq;
                f4v d = {0.0f, 0.0f, 0.0f, 0.0f};
#pragma unroll
                for (int kc = 0; kc < 2; ++kc) {
                    s8v Ah = *(const s8v*)(ah + 32 * kc);
                    s8v Al = *(const s8v*)(al + 32 * kc);
                    s8v Bh = *(const s8v*)(bh + 32 * kc);
                    s8v Bl = *(const s8v*)(bl + 32 * kc);
                    d = MFMA(Ah, Bh, d);
                    d = MFMA(Ah, Bl, d);
                    d = MFMA(Al, Bh, d);
                }
                int orow = 16 * mt + 4 * lq, ocol = 16 * nt + l15;
#pragma unroll
                for (int rr = 0; rr < 4; ++rr) {
                    float x = d[rr];
                    unsigned short h = f2bf(x);
                    WTH[(orow + rr) * 72 + ocol] = h;
                    WTL[(orow + rr) * 72 + ocol] = f2bf(x - bf2f(h));
                }
            }
            // qhF: waves 0..11, row = 8*wv + (ln>>3), 8 lanes per row
            if (wv < 12) {
                int row = 8 * wv + (ln >> 3), kq = ln & 7;
                float acc = 0.0f;
                const unsigned short* fh = FTH + row * 72 + 8 * kq;
                const unsigned short* fl = FTL + row * 72 + 8 * kq;
                const float* vvp = VVf + 8 * kq;
#pragma unroll
                for (int k = 0; k < 8; ++k)
                    acc += (bf2f(fh[k]) + bf2f(fl[k])) * vvp[k];
                acc += __shfl_xor(acc, 1);
                acc += __shfl_xor(acc, 2);
                acc += __shfl_xor(acc, 4);
                if ((ln & 7) == 0) QHF[row] = acc + pv;
            }
        }
        __syncthreads();   // B1: WT, qhF, Q-stage ready

        // ---- P2: QH lower tiles = Qstage + F^T W via MFMA; mirror; XU pack ----
        {
#pragma unroll
            for (int tt = 0; tt < 2; ++tt) if (tt < qcnt) {
                int T = wv + 16 * tt, mt, nt; tileMN(T, mt, nt);
                int orow = 16 * mt + 4 * lq, ocol = 16 * nt + l15;
                const unsigned short* ah = FTH + (16 * mt + l15) * 72 + 8 * lq;
                const unsigned short* al = FTL + (16 * mt + l15) * 72 + 8 * lq;
                const unsigned short* bh = WTH + (16 * nt + l15) * 72 + 8 * lq;
                const unsigned short* bl = WTL + (16 * nt + l15) * 72 + 8 * lq;
                f4v d;
#pragma unroll
                for (int rr = 0; rr < 4; ++rr)
                    d[rr] = QHf[(orow + rr) * 100 + ocol];    // C-init = staged Q
#pragma unroll
                for (int kc = 0; kc < 2; ++kc) {
                    s8v Ah = *(const s8v*)(ah + 32 * kc);
                    s8v Al = *(const s8v*)(al + 32 * kc);
                    s8v Bh = *(const s8v*)(bh + 32 * kc);
                    s8v Bl = *(const s8v*)(bl + 32 * kc);
                    d = MFMA(Ah, Bh, d);
                    d = MFMA(Ah, Bl, d);
                    d = MFMA(Al, Bh, d);
                }
#pragma unroll
                for (int rr = 0; rr < 4; ++rr)
                    QHf[(orow + rr) * 100 + ocol] = d[rr];
                if (mt > nt) {   // mirror to upper triangle
#pragma unroll
                    for (int rr = 0; rr < 4; ++rr)
                        QHf[ocol * 100 + orow + rr] = d[rr];
                }
                if (mt >= 4 && nt < 4) {   // ux tile -> XU (Qxu[x][u]) bf16 pack
#pragma unroll
                    for (int rr = 0; rr < 4; ++rr) {
                        float x = d[rr];
                        unsigned short h = f2bf(x);
                        XUH[ocol * 40 + (orow + rr - 64)] = h;
                        XUL[ocol * 40 + (orow + rr - 64)] = f2bf(x - bf2f(h));
                    }
                }
            }
        }
        __syncthreads();   // B2: QH (full, mirrored) ready

        // ---- P3: wave0 chol+Linv ; waves14/15 qh ; waves1-12 stage next FTbf ----
        if (wv == 0) {
            const int i = ln & 31;
            float a[32];
#pragma unroll
            for (int j4 = 0; j4 < 8; ++j4) {
                float4 v = *(const float4*)&QHf[(64 + i) * 100 + 64 + 4 * j4];
                a[4 * j4] = v.x; a[4 * j4 + 1] = v.y; a[4 * j4 + 2] = v.z; a[4 * j4 + 3] = v.w;
            }
#pragma unroll
            for (int j = 0; j < 32; ++j) {
                float dj = lanebc(a[j], j);
                float rj = rsqrtf(dj);
                a[j] *= rj;                        // lane i holds L[i][j] (i>=j); lane j: sqrt(dj)
#pragma unroll
                for (int k = j + 1; k < 32; ++k)
                    a[k] -= a[j] * lanebc(a[j], k);
            }
            float y[32];
#pragma unroll
            for (int r = 0; r < 32; ++r) {
                float acc0 = (r == i) ? 1.0f : 0.0f, acc1 = 0.0f;
#pragma unroll
                for (int j = 0; j < r; ++j) {
                    float lrj = lanebc(a[j], r);
                    if (j & 1) acc1 -= lrj * y[j]; else acc0 -= lrj * y[j];
                }
                // 1/L[r][r] recomputed from broadcast (saves rinv[32] VGPRs)
                y[r] = (acc0 + acc1) * __builtin_amdgcn_rcpf(lanebc(a[r], r));
            }
            if (ln < 32) {
#pragma unroll
                for (int r = 0; r < 32; ++r) LIf[r * 36 + ln] = y[r];
            }
        } else if (wv >= 14) {
            // qh[j] = qhF[j] + sum_i WT[j][i] c[i]
            int j = (wv == 14) ? ln : (64 + (ln & 31));
            if (wv == 14 || ln < 32) {
                float acc = QHF[j];
                const unsigned short* wh = WTH + j * 72;
                const unsigned short* wl = WTL + j * 72;
#pragma unroll 4
                for (int i = 0; i < 64; ++i)
                    acc += (bf2f(wh[i]) + bf2f(wl[i])) * CVf[i];
                QHf[j * 100 + 96] = acc;
            }
        } else if (wv <= 12) {
            const int tau = tid - 64, kk = tau & 63, cq = tau >> 6;
#pragma unroll
            for (int q = 0; q < 2; ++q) {
                float4 v = fp4[q];
                int col0 = 8 * cq + 4 * q;
#pragma unroll
                for (int e = 0; e < 4; ++e) {
                    int col = col0 + e;
                    float x = (e == 0) ? v.x : (e == 1) ? v.y : (e == 2) ? v.z : v.w;
                    unsigned short h = f2bf(x);
                    FTH[col * 72 + kk] = h;
                    FTL[col * 72 + kk] = f2bf(x - bf2f(h));
                }
            }
        }
        __syncthreads();   // B3: LI, qh, next-FT ready

        // ---- P4: T1T = (LI @ [Qux|qu])^T; 16 groups x 2 rows ----
        {
            const int c = tid & 63, g = tid >> 6;
            float a0 = 0.0f, a1 = 0.0f;
#pragma unroll
            for (int j4 = 0; j4 < 8; ++j4) {
                float4 qv = *(const float4*)&QHf[c * 100 + 64 + 4 * j4];  // Qux[j][c] via symmetry
                float4 l0 = *(const float4*)&LIf[(2 * g) * 36 + 4 * j4];
                float4 l1 = *(const float4*)&LIf[(2 * g + 1) * 36 + 4 * j4];
                a0 += dot4(l0, qv);
                a1 += dot4(l1, qv);
            }
            *(float2*)&T1f[c * 36 + 2 * g] = make_float2(a0, a1);
            if (tid < 32) {   // qu column
                float aq = 0.0f;
#pragma unroll 4
                for (int j = 0; j < 32; ++j)
                    aq += LIf[tid * 36 + j] * QHf[(64 + j) * 100 + 96];
                T1f[64 * 36 + tid] = aq;
            }
        }
        __syncthreads();   // B4: T1T ready

        // ---- P5: K = -(LI^T T1) -> KTbf + ws ; kvec ; 16 groups x 2 cols ----
        {
            const int c = tid & 63, g = tid >> 6;
            float a0 = 0.0f, a1 = 0.0f;
#pragma unroll
            for (int i4 = 0; i4 < 8; ++i4) {
                float4 tv = *(const float4*)&T1f[c * 36 + 4 * i4];
#pragma unroll
                for (int ii = 0; ii < 4; ++ii) {
                    float2 li = *(const float2*)&LIf[(4 * i4 + ii) * 36 + 2 * g];
                    float tvi = (ii == 0) ? tv.x : (ii == 1) ? tv.y : (ii == 2) ? tv.z : tv.w;
                    a0 += tvi * li.x;
                    a1 += tvi * li.y;
                }
            }
            float k0 = -a0, k1 = -a1;
            unsigned short h0 = f2bf(k0), h1 = f2bf(k1);
            *(ushort2*)&KTH[c * 40 + 2 * g] = make_ushort2(h0, h1);
            *(ushort2*)&KTL[c * 40 + 2 * g] = make_ushort2(f2bf(k0 - bf2f(h0)), f2bf(k1 - bf2f(h1)));
            float* wrow = wsK + bt * WSK_STRIDE;
            wrow[(2 * g) * 65 + c]     = k0;
            wrow[(2 * g + 1) * 65 + c] = k1;
            if (tid < 32) {   // kvec
                float aq = 0.0f;
#pragma unroll 4
                for (int i = 0; i < 32; ++i)
                    aq += LIf[i * 36 + tid] * T1f[64 * 36 + i];
                KVf[tid] = -aq;
                wsK[bt * WSK_STRIDE + tid * 65 + 64] = -aq;
            }
        }
        __syncthreads();   // B5: KTbf, kvec ready

        // ---- P6a: VRAW = Qxx + Qxu K via MFMA (16 tiles, 1/wave) ----
        {
            int mt = wv >> 2, nt = wv & 3;
            int orow = 16 * mt + 4 * lq, ocol = 16 * nt + l15;
            f4v d;
#pragma unroll
            for (int rr = 0; rr < 4; ++rr)
                d[rr] = QHf[(orow + rr) * 100 + ocol];
            s8v Ah = *(const s8v*)(XUH + (16 * mt + l15) * 40 + 8 * lq);
            s8v Al = *(const s8v*)(XUL + (16 * mt + l15) * 40 + 8 * lq);
            s8v Bh = *(const s8v*)(KTH + (16 * nt + l15) * 40 + 8 * lq);
            s8v Bl = *(const s8v*)(KTL + (16 * nt + l15) * 40 + 8 * lq);
            d = MFMA(Ah, Bh, d);
            d = MFMA(Ah, Bl, d);
            d = MFMA(Al, Bh, d);
#pragma unroll
            for (int rr = 0; rr < 4; ++rr)
                VRW[(orow + rr) * 72 + ocol] = d[rr];
        }
        __syncthreads();   // B6: VRAW ready

        // ---- P6b: symmetrize -> Vbf hi/lo ; vn ----
        if (tid < 256) {
            const int rg = tid >> 4, cgv = tid & 15;
            float4 m0[4], m1[4];
#pragma unroll
            for (int rr = 0; rr < 4; ++rr) {
                m0[rr] = *(const float4*)&VRW[(4 * rg + rr) * 72 + 4 * cgv];
                m1[rr] = *(const float4*)&VRW[(4 * cgv + rr) * 72 + 4 * rg];
            }
#pragma unroll
            for (int rr = 0; rr < 4; ++rr) {
                float s[4];
                s[0] = 0.5f * (m0[rr].x + ((float*)&m1[0])[rr]);
                s[1] = 0.5f * (m0[rr].y + ((float*)&m1[1])[rr]);
                s[2] = 0.5f * (m0[rr].z + ((float*)&m1[2])[rr]);
                s[3] = 0.5f * (m0[rr].w + ((float*)&m1[3])[rr]);
                unsigned short h[4], lo[4];
#pragma unroll
                for (int cc = 0; cc < 4; ++cc) {
                    h[cc]  = f2bf(s[cc]);
                    lo[cc] = f2bf(s[cc] - bf2f(h[cc]));
                }
                ushort4 hv = make_ushort4(h[0], h[1], h[2], h[3]);
                ushort4 lv = make_ushort4(lo[0], lo[1], lo[2], lo[3]);
                *(ushort4*)&VBH[(4 * rg + rr) * 72 + 4 * cgv] = hv;
                *(ushort4*)&VBL[(4 * rg + rr) * 72 + 4 * cgv] = lv;
            }
        } else if (tid < 320) {
            const int r = tid & 63;
            float acc = QHf[r * 100 + 96];
#pragma unroll
            for (int j4 = 0; j4 < 8; ++j4) {
                float4 qv = *(const float4*)&QHf[r * 100 + 64 + 4 * j4];
                float4 kv = *(const float4*)&KVf[4 * j4];
                acc += dot4(qv, kv);
            }
            VVf[r] = acc;
        }
        __syncthreads();   // B7: V, v ready for next step
    }

    // ================= forward rollout =================
    float* sm = (float*)smb;
    {
        const size_t bt0 = (size_t)b * TT;
#pragma unroll
        for (int it = 0; it < 2; ++it) {
            int q = tid + 1024 * it;
            if (q < 1536) {
                int row = q / 24, g = q % 24;
                const float* src = (g < 16) ? (A + (bt0 * 64 + row) * 64 + 4 * g)
                                            : (B + (bt0 * 64 + row) * 32 + 4 * (g - 16));
                *(float4*)&sm[AB0 + row * 100 + 4 * g] = *(const float4*)src;
            }
        }
#pragma unroll
        for (int i = 0; i < 3; ++i) {
            int idx = tid + 1024 * i;
            if (idx < 2080) {
                int j = idx / 65, c = idx - 65 * j;
                sm[KF0 + j * 68 + c] = wsK[bt0 * WSK_STRIDE + idx];
            }
        }
        if (tid < 64) sm[XB0 + tid] = xinit[b * 64 + tid];
    }
    __syncthreads();

    for (int t = 0; t < TT; ++t) {
        const size_t bt  = (size_t)b * TT + t;
        const size_t btn = (size_t)b * TT + ((t < TT - 1) ? (t + 1) : t);
        const int cur = t & 1;
        const int abC = cur ? AB1 : AB0, abN = cur ? AB0 : AB1;
        const int kfC = cur ? KF1 : KF0, kfN = cur ? KF0 : KF1;
        const int xbC = cur ? XB1 : XB0, xbN = cur ? XB0 : XB1;

        // waves 8-11 prefetch next-step AB, K; waves 4-7 load c for this step
        float4 abpre[6];
        float kpre[9];
        float cpre = 0.0f;
        if (tid >= 512 && tid < 768) {
            const int t2 = tid - 512;
#pragma unroll
            for (int it = 0; it < 6; ++it) {
                int q = t2 + 256 * it, row = q / 24, g = q % 24;
                const float* src = (g < 16) ? (A + (btn * 64 + row) * 64 + 4 * g)
                                            : (B + (btn * 64 + row) * 32 + 4 * (g - 16));
                abpre[it] = *(const float4*)src;
            }
#pragma unroll
            for (int i = 0; i < 9; ++i) {
                int idx = t2 + 256 * i;
                kpre[i] = (idx < 2080) ? wsK[btn * WSK_STRIDE + idx] : 0.0f;
            }
        }
        if (tid >= 256 && tid < 512)
            cpre = c1[bt * 64 + ((tid - 256) >> 2)];

        // ---- phase A: waves 0-3: u = Kx + k ; waves 4-7: ax = Ax + c, emit x ----
        if (tid < 256) {
            const int j = tid >> 3, q = tid & 7;
            float4 k0 = *(const float4*)&sm[kfC + j * 68 + 8 * q];
            float4 k1 = *(const float4*)&sm[kfC + j * 68 + 8 * q + 4];
            float4 x0 = *(const float4*)&sm[xbC + 8 * q];
            float4 x1 = *(const float4*)&sm[xbC + 8 * q + 4];
            float pa = dot4(k0, x0) + dot4(k1, x1);
            pa += __shfl_xor(pa, 1);
            pa += __shfl_xor(pa, 2);
            pa += __shfl_xor(pa, 4);
            if (q == 0) {
                float u = pa + sm[kfC + j * 68 + 64];
                sm[UBO + j] = u;
                out[bt * 96 + 64 + j] = u;
            }
        } else if (tid < 512) {
            const int r = (tid - 256) >> 2, q = tid & 3;
            float pa = 0.0f;
#pragma unroll
            for (int e4 = 0; e4 < 4; ++e4) {
                float4 av = *(const float4*)&sm[abC + r * 100 + 16 * q + 4 * e4];
                float4 xv = *(const float4*)&sm[xbC + 16 * q + 4 * e4];
                pa += dot4(av, xv);
            }
            pa += __shfl_xor(pa, 1);
            pa += __shfl_xor(pa, 2);
            if (q == 0) sm[AXO + r] = pa + cpre;
            if (q == 1) out[bt * 96 + r] = sm[xbC + r];
        }
        __syncthreads();

        // ---- phase B: waves 0-3: xn = ax + B u ; waves 8-11: stage next ----
        if (tid < 256) {
            const int r = tid >> 2, q = tid & 3;
            float4 b0 = *(const float4*)&sm[abC + r * 100 + 64 + 8 * q];
            float4 b1 = *(const float4*)&sm[abC + r * 100 + 64 + 8 * q + 4];
            float4 u0 = *(const float4*)&sm[UBO + 8 * q];
            float4 u1 = *(const float4*)&sm[UBO + 8 * q + 4];
            float pa = dot4(b0, u0) + dot4(b1, u1);
            pa += __shfl_xor(pa, 1);
            pa += __shfl_xor(pa, 2);
            if (q == 0) sm[xbN + r] = sm[AXO + r] + pa;
        } else if (tid >= 512 && tid < 768) {
            const int t2 = tid - 512;
#pragma unroll
            for (int it = 0; it < 6; ++it) {
                int q = t2 + 256 * it, row = q / 24, g = q % 24;
                *(float4*)&sm[abN + row * 100 + 4 * g] = abpre[it];
            }
#pragma unroll
            for (int i = 0; i < 9; ++i) {
                int idx = t2 + 256 * i;
                if (idx < 2080) {
                    int j = idx / 65, c = idx - 65 * j;
                    sm[kfN + j * 68 + c] = kpre[i];
                }
            }
        }
        __syncthreads();
    }
}

extern "C" void kernel_launch(void* const* d_in, const int* in_sizes, int n_in,
                              void* d_out, int out_size, void* d_ws, size_t ws_size,
                              hipStream_t stream) {
    (void)in_sizes; (void)n_in; (void)out_size;
    const float* Q  = (const float*)d_in[0];
    const float* p  = (const float*)d_in[1];
    const float* A  = (const float*)d_in[2];
    const float* B  = (const float*)d_in[3];
    const float* c1 = (const float*)d_in[4];
    const float* xi = (const float*)d_in[5];
    if (ws_size < (size_t)NB * TT * WSK_STRIDE * sizeof(float)) return;
    lqr_kernel<<<NB, 1024, 0, stream>>>(Q, p, A, B, c1, xi, (float*)d_out, (float*)d_ws);
}

// Round 7
// 11279.581 us; speedup vs baseline: 1.0463x; 1.0463x over previous
//
#include <hip/hip_runtime.h>
#include <math.h>

#define TT 512
#define NB 16

// ---------------- LDS byte offsets (backward) ----------------
#define QH_B   0        // QH  [96][100] f32 (col 96 = qh)
#define LI_B   38400    // LI  [32][36]  f32   LI[r][i] = Linv[r][i]
#define LIT_B  43008    // LIT [32][36]  f32   LIT[i][r] = Linv[r][i]  (transposed copy)
#define KV_B   47616    // k [32] f32
#define VBH_B  47744    // Vbf-hi [64][72] us
#define VBL_B  56960    // Vbf-lo
#define FTH_B  66176    // FTbf-hi [96][72] us   FT[c][k] = F[k][c]
#define FTL_B  80000
#define WTH_B  93824    // WTbf-hi [96][72] us   WT[c][i] = W[i][c]
#define WTL_B  107648
#define T1S_B  93824    // T1S [65][36] f32 (aliases WT; live only in P45 when WT is dead)
#define XUH_B  121472   // QXUbf-hi [64][40] us  XU[xrow][ucol]
#define XUL_B  126592
#define KTH_B  131712   // KTbf-hi [64][40] us   KT[c][j] = K[j][c]
#define KTL_B  136832
#define QHF_B  141952   // qhF [96] f32
#define VV_B   142336   // v [64] f32
#define CV_B   142592   // c [64] f32
#define SMB    142848

// ---------------- forward overlay (float offsets) ----------------
#define AB0 0
#define AB1 6400
#define KF0 12800
#define KF1 14976
#define XB0 17152
#define XB1 17216
#define UBO 17280
#define AXO 17312

#define WSK_STRIDE 2080   // per (b,t): rows j: [j*65 + c], col 64 = k

typedef __attribute__((ext_vector_type(8))) short s8v;
typedef __attribute__((ext_vector_type(4))) float f4v;

__device__ __forceinline__ float lanebc(float x, int lane) {
    return __int_as_float(__builtin_amdgcn_readlane(__float_as_int(x), lane));
}
__device__ __forceinline__ float dot4(float4 a, float4 b) {
    return a.x * b.x + a.y * b.y + a.z * b.z + a.w * b.w;
}
__device__ __forceinline__ unsigned short f2bf(float x) {
    unsigned int u = __float_as_uint(x);
    u += 0x7FFFu + ((u >> 16) & 1u);           // RNE
    return (unsigned short)(u >> 16);
}
__device__ __forceinline__ float bf2f(unsigned short h) {
    return __uint_as_float(((unsigned int)h) << 16);
}
// lower-triangular 16x16 tile enumeration: T=0..20 -> (mt,nt), nt<=mt
__device__ __forceinline__ void tileMN(int T, int& mt, int& nt) {
    mt = (T >= 15) ? 5 : (T >= 10) ? 4 : (T >= 6) ? 3 : (T >= 3) ? 2 : (T >= 1) ? 1 : 0;
    nt = T - mt * (mt + 1) / 2;
}
#define MFMA(a,b,c) __builtin_amdgcn_mfma_f32_16x16x32_bf16((a),(b),(c),0,0,0)

__launch_bounds__(512, 2)
__global__ void lqr_kernel(const float* __restrict__ Q, const float* __restrict__ P,
                           const float* __restrict__ A, const float* __restrict__ B,
                           const float* __restrict__ c1, const float* __restrict__ xinit,
                           float* __restrict__ out, float* __restrict__ ws)
{
    __shared__ __align__(16) unsigned char smb[SMB];
    float*          QHf = (float*)(smb + QH_B);
    float*          LIf = (float*)(smb + LI_B);
    float*          LIT = (float*)(smb + LIT_B);
    float*          T1S = (float*)(smb + T1S_B);
    unsigned short* VBH = (unsigned short*)(smb + VBH_B);
    unsigned short* VBL = (unsigned short*)(smb + VBL_B);
    unsigned short* FTH = (unsigned short*)(smb + FTH_B);
    unsigned short* FTL = (unsigned short*)(smb + FTL_B);
    unsigned short* WTH = (unsigned short*)(smb + WTH_B);
    unsigned short* WTL = (unsigned short*)(smb + WTL_B);
    unsigned short* XUH = (unsigned short*)(smb + XUH_B);
    unsigned short* XUL = (unsigned short*)(smb + XUL_B);
    unsigned short* KTH = (unsigned short*)(smb + KTH_B);
    unsigned short* KTL = (unsigned short*)(smb + KTL_B);
    float*          QHF = (float*)(smb + QHF_B);
    float*          VVf = (float*)(smb + VV_B);
    float*          CVf = (float*)(smb + CV_B);
    float*          KVf = (float*)(smb + KV_B);

    const int tid = threadIdx.x;
    const int b   = blockIdx.x;
    const int wv  = tid >> 6;   // 0..7
    const int ln  = tid & 63;
    const int l15 = ln & 15;
    const int lq  = ln >> 4;
    float* wsK = ws;

    const int qcnt = (wv < 5) ? 3 : 2;      // Q lower tiles per wave: {wv, wv+8, wv+16}
    const int qr = ln >> 2, qc4 = ln & 3;   // Q-stage lane mapping

    // ---- prologue: issue Q loads for t=511 immediately ----
    float4 qreg[3];
    {
        const float* Qg = Q + ((size_t)b * TT + (TT - 1)) * 9216;
#pragma unroll
        for (int tt = 0; tt < 3; ++tt) if (tt < qcnt) {
            int T = wv + 8 * tt, mt, nt; tileMN(T, mt, nt);
            qreg[tt] = *(const float4*)&Qg[(16 * mt + qr) * 96 + 16 * nt + 4 * qc4];
        }
    }

    // ---------------- init: Vbf=0, v=0, stage FTbf for t=511 ----------------
    if (tid < 384) {
        const size_t bt = (size_t)b * TT + (TT - 1);
        const int kk = tid & 63, cq = tid >> 6;
#pragma unroll
        for (int q = 0; q < 4; ++q) {
            const float* src = (cq < 4) ? (A + (bt * 64 + kk) * 64 + 16 * cq + 4 * q)
                                        : (B + (bt * 64 + kk) * 32 + 16 * (cq - 4) + 4 * q);
            float4 v = *(const float4*)src;
#pragma unroll
            for (int e = 0; e < 4; ++e) {
                int col = 16 * cq + 4 * q + e;
                float x = (e == 0) ? v.x : (e == 1) ? v.y : (e == 2) ? v.z : v.w;
                unsigned short h = f2bf(x);
                FTH[col * 72 + kk] = h;
                FTL[col * 72 + kk] = f2bf(x - bf2f(h));
            }
        }
    } else {
        float* vb = (float*)VBH;   // zero Vbf hi+lo (4608 floats contiguous)
        for (int i = tid - 384; i < 4608; i += 128) vb[i] = 0.0f;
        if (tid >= 448) VVf[tid - 448] = 0.0f;
    }
    __syncthreads();

    // ================= backward Riccati recursion =================
    for (int t = TT - 1; t >= 0; --t) {
        const size_t bt  = (size_t)b * TT + t;
        const size_t btp = (size_t)b * TT + ((t > 0) ? (t - 1) : 0);

        // ---- P1-start: commit prefetched Q_t tiles; issue next Q; prefetch A/B ----
#pragma unroll
        for (int tt = 0; tt < 3; ++tt) if (tt < qcnt) {
            int T = wv + 8 * tt, mt, nt; tileMN(T, mt, nt);
            *(float4*)&QHf[(16 * mt + qr) * 100 + 16 * nt + 4 * qc4] = qreg[tt];
        }
        {
            const float* Qg = Q + btp * 9216;
#pragma unroll
            for (int tt = 0; tt < 3; ++tt) if (tt < qcnt) {
                int T = wv + 8 * tt, mt, nt; tileMN(T, mt, nt);
                qreg[tt] = *(const float4*)&Qg[(16 * mt + qr) * 96 + 16 * nt + 4 * qc4];
            }
        }
        float4 fp4[4];
        if (tid >= 128) {                       // waves 2..7 stage next-step FT (in P45)
            const int tau = tid - 128, kk = tau & 63, cq = tau >> 6;   // cq 0..5
#pragma unroll
            for (int q = 0; q < 4; ++q) {
                const float* src = (cq < 4) ? (A + (btp * 64 + kk) * 64 + 16 * cq + 4 * q)
                                            : (B + (btp * 64 + kk) * 32 + 16 * (cq - 4) + 4 * q);
                fp4[q] = *(const float4*)src;
            }
        }
        if (wv == 7 && ln < 16)
            *(float4*)&CVf[4 * ln] = *(const float4*)&c1[bt * 64 + 4 * ln];
        float pv = 0.0f;
        if (ln < 48 && (ln & 3) == 0) pv = P[bt * 96 + 12 * wv + (ln >> 2)];

        // shared tile body for QH = Qstage + F^T W (used by P2a and P2b)
        auto qhTile = [&](int T) {
            int mt, nt; tileMN(T, mt, nt);
            int orow = 16 * mt + 4 * lq, ocol = 16 * nt + l15;
            const unsigned short* ah = FTH + (16 * mt + l15) * 72 + 8 * lq;
            const unsigned short* al = FTL + (16 * mt + l15) * 72 + 8 * lq;
            const unsigned short* bh = WTH + (16 * nt + l15) * 72 + 8 * lq;
            const unsigned short* bl = WTL + (16 * nt + l15) * 72 + 8 * lq;
            f4v d;
#pragma unroll
            for (int rr = 0; rr < 4; ++rr)
                d[rr] = QHf[(orow + rr) * 100 + ocol];    // C-init = staged Q
#pragma unroll
            for (int kc = 0; kc < 2; ++kc) {
                s8v Ah = *(const s8v*)(ah + 32 * kc);
                s8v Al = *(const s8v*)(al + 32 * kc);
                s8v Bh = *(const s8v*)(bh + 32 * kc);
                s8v Bl = *(const s8v*)(bl + 32 * kc);
                d = MFMA(Ah, Bh, d);
                d = MFMA(Ah, Bl, d);
                d = MFMA(Al, Bh, d);
            }
#pragma unroll
            for (int rr = 0; rr < 4; ++rr)
                QHf[(orow + rr) * 100 + ocol] = d[rr];
            if (mt > nt) {   // mirror to upper triangle
#pragma unroll
                for (int rr = 0; rr < 4; ++rr)
                    QHf[ocol * 100 + orow + rr] = d[rr];
            }
            if (mt >= 4 && nt < 4) {   // ux tile -> XU (Qxu[x][u]) bf16 pack
#pragma unroll
                for (int rr = 0; rr < 4; ++rr) {
                    float x = d[rr];
                    unsigned short h = f2bf(x);
                    XUH[ocol * 40 + (orow + rr - 64)] = h;
                    XUL[ocol * 40 + (orow + rr - 64)] = f2bf(x - bf2f(h));
                }
            }
        };

        // ---- P1: GEMM1 (WT = (VF)^T via MFMA, 24 tiles, 3/wave) + qhF = p + F^T v ----
        {
#pragma unroll
            for (int tt = 0; tt < 3; ++tt) {
                int T = wv * 3 + tt, mt = T >> 2, nt = T & 3;
                const unsigned short* ah = FTH + (16 * mt + l15) * 72 + 8 * lq;
                const unsigned short* al = FTL + (16 * mt + l15) * 72 + 8 * lq;
                const unsigned short* bh = VBH + (16 * nt + l15) * 72 + 8 * lq;
                const unsigned short* bl = VBL + (16 * nt + l15) * 72 + 8 * lq;
                f4v d = {0.0f, 0.0f, 0.0f, 0.0f};
#pragma unroll
                for (int kc = 0; kc < 2; ++kc) {
                    s8v Ah = *(const s8v*)(ah + 32 * kc);
                    s8v Al = *(const s8v*)(al + 32 * kc);
                    s8v Bh = *(const s8v*)(bh + 32 * kc);
                    s8v Bl = *(const s8v*)(bl + 32 * kc);
                    d = MFMA(Ah, Bh, d);
                    d = MFMA(Ah, Bl, d);
                    d = MFMA(Al, Bh, d);
                }
                int orow = 16 * mt + 4 * lq, ocol = 16 * nt + l15;
#pragma unroll
                for (int rr = 0; rr < 4; ++rr) {
                    float x = d[rr];
                    unsigned short h = f2bf(x);
                    WTH[(orow + rr) * 72 + ocol] = h;
                    WTL[(orow + rr) * 72 + ocol] = f2bf(x - bf2f(h));
                }
            }
            // qhF: row = 12*wv + (ln>>2), k-quarter = ln&3
            if (ln < 48) {
                int row = 12 * wv + (ln >> 2), kq = ln & 3;
                float acc = 0.0f;
                const unsigned short* fh = FTH + row * 72 + 16 * kq;
                const unsigned short* fl = FTL + row * 72 + 16 * kq;
                const float* vvp = VVf + 16 * kq;
#pragma unroll
                for (int k = 0; k < 16; ++k)
                    acc += (bf2f(fh[k]) + bf2f(fl[k])) * vvp[k];
                acc += __shfl_xor(acc, 1);
                acc += __shfl_xor(acc, 2);
                if ((ln & 3) == 0) QHF[row] = acc + pv;
            }
        }
        __syncthreads();   // B1: WT, qhF, Q-stage ready

        // ---- P2a: 8 tiles (1/wave), uu tiles (14,19,20) first ----
        {
            int T = (wv == 0) ? 14 : (wv == 1) ? 19 : (wv == 2) ? 20 :
                    (wv == 3) ? 0  : (wv == 4) ? 1  : (wv == 5) ? 2  :
                    (wv == 6) ? 3  : 4;
            qhTile(T);
        }
        __syncthreads();   // B2a: Quu ready

        // ---- P2b: wave0 chol+Linv  ∥  waves1-6: 2 tiles  ∥  wave7: 1 tile + qh ----
        if (wv == 0) {
            const int i = ln & 31;
            float a[32];
#pragma unroll
            for (int j4 = 0; j4 < 8; ++j4) {
                float4 v = *(const float4*)&QHf[(64 + i) * 100 + 64 + 4 * j4];
                a[4 * j4] = v.x; a[4 * j4 + 1] = v.y; a[4 * j4 + 2] = v.z; a[4 * j4 + 3] = v.w;
            }
#pragma unroll
            for (int j = 0; j < 32; ++j) {
                float dj = lanebc(a[j], j);
                float rj = rsqrtf(dj);
                a[j] *= rj;
#pragma unroll
                for (int k = j + 1; k < 32; ++k)
                    a[k] -= a[j] * lanebc(a[j], k);
            }
            float y[32];
#pragma unroll
            for (int r = 0; r < 32; ++r) {
                float acc0 = (r == i) ? 1.0f : 0.0f, acc1 = 0.0f;
#pragma unroll
                for (int j = 0; j < r; ++j) {
                    float lrj = lanebc(a[j], r);
                    if (j & 1) acc1 -= lrj * y[j]; else acc0 -= lrj * y[j];
                }
                y[r] = (acc0 + acc1) * __builtin_amdgcn_rcpf(lanebc(a[r], r));
            }
            if (ln < 32) {
#pragma unroll
                for (int r = 0; r < 32; ++r) LIf[r * 36 + ln] = y[r];
#pragma unroll
                for (int r4 = 0; r4 < 8; ++r4)
                    *(float4*)&LIT[ln * 36 + 4 * r4] =
                        make_float4(y[4 * r4], y[4 * r4 + 1], y[4 * r4 + 2], y[4 * r4 + 3]);
            }
        } else {
            const int Ta = (wv == 1) ? 5 : (wv == 2) ? 7 : (wv == 3) ? 9 :
                           (wv == 4) ? 11 : (wv == 5) ? 13 : (wv == 6) ? 16 : 18;
            qhTile(Ta);
            if (wv <= 6) {
                const int Tb = (wv == 1) ? 6 : (wv == 2) ? 8 : (wv == 3) ? 10 :
                               (wv == 4) ? 12 : (wv == 5) ? 15 : 17;
                qhTile(Tb);
            } else {
                // wave7: qh[j] = qhF[j] + sum_i WT[j][i] c[i]
#pragma unroll
                for (int pass = 0; pass < 2; ++pass) {
                    int j = pass ? (64 + (ln & 31)) : ln;
                    if (pass && ln >= 32) break;
                    float acc = QHF[j];
                    const unsigned short* wh = WTH + j * 72;
                    const unsigned short* wl = WTL + j * 72;
#pragma unroll 4
                    for (int i = 0; i < 64; ++i)
                        acc += (bf2f(wh[i]) + bf2f(wl[i])) * CVf[i];
                    QHf[j * 100 + 96] = acc;
                }
            }
        }
        __syncthreads();   // B3: QH full, LI/LIT, qh ready

        // ---- P45: merged solve. 8-lane group per column c: T1 local, K = -(LI^T T1) ----
        {
            const int g = tid >> 3, q = tid & 7;
            float4 qc[8];
#pragma unroll
            for (int j4 = 0; j4 < 8; ++j4)
                qc[j4] = *(const float4*)&QHf[g * 100 + 64 + 4 * j4];   // Qux[j][g] via symmetry
            float t1v[4];
#pragma unroll
            for (int s = 0; s < 4; ++s) {
                float acc = 0.0f;
#pragma unroll
                for (int j4 = 0; j4 < 8; ++j4)
                    acc += dot4(*(const float4*)&LIf[(4 * q + s) * 36 + 4 * j4], qc[j4]);
                t1v[s] = acc;
            }
            *(float4*)&T1S[g * 36 + 4 * q] = make_float4(t1v[0], t1v[1], t1v[2], t1v[3]);
            float4 ts[8];
#pragma unroll
            for (int i4 = 0; i4 < 8; ++i4)
                ts[i4] = *(const float4*)&T1S[g * 36 + 4 * i4];   // same-wave RAW, lgkmcnt-ordered
            float* wrow = wsK + bt * WSK_STRIDE;
#pragma unroll
            for (int s = 0; s < 4; ++s) {
                int r = 4 * q + s;
                float acc = 0.0f;
#pragma unroll
                for (int i4 = 0; i4 < 8; ++i4)
                    acc += dot4(*(const float4*)&LIT[r * 36 + 4 * i4], ts[i4]);
                float kv = -acc;
                unsigned short h = f2bf(kv);
                KTH[g * 40 + r] = h;
                KTL[g * 40 + r] = f2bf(kv - bf2f(h));
                wrow[r * 65 + g] = kv;
            }
            if (g == 0) {   // qu column -> kvec
                float t1q[4];
#pragma unroll
                for (int s = 0; s < 4; ++s) {
                    float acc = 0.0f;
#pragma unroll
                    for (int j4 = 0; j4 < 8; ++j4) {
                        float4 li = *(const float4*)&LIf[(4 * q + s) * 36 + 4 * j4];
                        float4 qv = make_float4(QHf[(64 + 4 * j4) * 100 + 96],
                                                QHf[(65 + 4 * j4) * 100 + 96],
                                                QHf[(66 + 4 * j4) * 100 + 96],
                                                QHf[(67 + 4 * j4) * 100 + 96]);
                        acc += dot4(li, qv);
                    }
                    t1q[s] = acc;
                }
                *(float4*)&T1S[64 * 36 + 4 * q] = make_float4(t1q[0], t1q[1], t1q[2], t1q[3]);
                float4 tq[8];
#pragma unroll
                for (int i4 = 0; i4 < 8; ++i4)
                    tq[i4] = *(const float4*)&T1S[64 * 36 + 4 * i4];
#pragma unroll
                for (int s = 0; s < 4; ++s) {
                    int r = 4 * q + s;
                    float acc = 0.0f;
#pragma unroll
                    for (int i4 = 0; i4 < 8; ++i4)
                        acc += dot4(*(const float4*)&LIT[r * 36 + 4 * i4], tq[i4]);
                    KVf[r] = -acc;
                    wrow[r * 65 + 64] = -acc;
                }
            }
            // FT staging for next step (waves 2..7; fp4 prefetched at P1-start)
            if (tid >= 128) {
                const int tau = tid - 128, kk = tau & 63, cq = tau >> 6;
#pragma unroll
                for (int q2 = 0; q2 < 4; ++q2) {
                    float4 v = fp4[q2];
#pragma unroll
                    for (int e = 0; e < 4; ++e) {
                        int col = 16 * cq + 4 * q2 + e;
                        float x = (e == 0) ? v.x : (e == 1) ? v.y : (e == 2) ? v.z : v.w;
                        unsigned short h = f2bf(x);
                        FTH[col * 72 + kk] = h;
                        FTL[col * 72 + kk] = f2bf(x - bf2f(h));
                    }
                }
            }
        }
        __syncthreads();   // B45: KT, kvec, next-FT ready

        // ---- P6: Vn = Qxx + Qxu K via MFMA (16 tiles, 2/wave) -> Vbf direct; vn ----
        {
#pragma unroll
            for (int tt = 0; tt < 2; ++tt) {
                int T = 2 * wv + tt, mt = T >> 2, nt = T & 3;
                int orow = 16 * mt + 4 * lq, ocol = 16 * nt + l15;
                f4v d;
#pragma unroll
                for (int rr = 0; rr < 4; ++rr)
                    d[rr] = QHf[(orow + rr) * 100 + ocol];
                s8v Ah = *(const s8v*)(XUH + (16 * mt + l15) * 40 + 8 * lq);
                s8v Al = *(const s8v*)(XUL + (16 * mt + l15) * 40 + 8 * lq);
                s8v Bh = *(const s8v*)(KTH + (16 * nt + l15) * 40 + 8 * lq);
                s8v Bl = *(const s8v*)(KTL + (16 * nt + l15) * 40 + 8 * lq);
                d = MFMA(Ah, Bh, d);
                d = MFMA(Ah, Bl, d);
                d = MFMA(Al, Bh, d);
#pragma unroll
                for (int rr = 0; rr < 4; ++rr) {
                    float x = d[rr];
                    unsigned short h = f2bf(x);
                    VBH[(orow + rr) * 72 + ocol] = h;
                    VBL[(orow + rr) * 72 + ocol] = f2bf(x - bf2f(h));
                }
            }
            // vn[r] = qh[r] + sum_j Qxu[r][j]*k[j]; 8 lanes per row
            {
                int r = 8 * wv + (ln >> 3), kq = ln & 7;
                float acc = 0.0f;
#pragma unroll
                for (int e = 0; e < 4; ++e) {
                    int j = 4 * kq + e;
                    acc += QHf[r * 100 + 64 + j] * KVf[j];
                }
                acc += __shfl_xor(acc, 1);
                acc += __shfl_xor(acc, 2);
                acc += __shfl_xor(acc, 4);
                if (kq == 0) VVf[r] = acc + QHf[r * 100 + 96];
            }
        }
        __syncthreads();   // Bend: V, v ready for next step
    }

    // ================= forward rollout (as R4) =================
    float* sm = (float*)smb;
    {
        const size_t bt0 = (size_t)b * TT;
#pragma unroll
        for (int it = 0; it < 3; ++it) {
            int q = tid + 512 * it, row = q / 24, g = q % 24;
            const float* src = (g < 16) ? (A + (bt0 * 64 + row) * 64 + 4 * g)
                                        : (B + (bt0 * 64 + row) * 32 + 4 * (g - 16));
            *(float4*)&sm[AB0 + row * 100 + 4 * g] = *(const float4*)src;
        }
#pragma unroll
        for (int i = 0; i < 5; ++i) {
            int idx = tid + 512 * i;
            if (idx < 2080) {
                int j = idx / 65, c = idx - 65 * j;
                sm[KF0 + j * 68 + c] = wsK[bt0 * WSK_STRIDE + idx];
            }
        }
        if (tid < 64) sm[XB0 + tid] = xinit[b * 64 + tid];
    }
    __syncthreads();

    for (int t = 0; t < TT; ++t) {
        const size_t bt  = (size_t)b * TT + t;
        const size_t btn = (size_t)b * TT + ((t < TT - 1) ? (t + 1) : t);
        const int cur = t & 1;
        const int abC = cur ? AB1 : AB0, abN = cur ? AB0 : AB1;
        const int kfC = cur ? KF1 : KF0, kfN = cur ? KF0 : KF1;
        const int xbC = cur ? XB1 : XB0, xbN = cur ? XB0 : XB1;

        float4 abpre[6];
        float kpre[9];
        float cpre = 0.0f;
        if (tid >= 256) {
            const int t2 = tid - 256;
#pragma unroll
            for (int it = 0; it < 6; ++it) {
                int q = t2 + 256 * it, row = q / 24, g = q % 24;
                const float* src = (g < 16) ? (A + (btn * 64 + row) * 64 + 4 * g)
                                            : (B + (btn * 64 + row) * 32 + 4 * (g - 16));
                abpre[it] = *(const float4*)src;
            }
#pragma unroll
            for (int i = 0; i < 9; ++i) {
                int idx = t2 + 256 * i;
                kpre[i] = (idx < 2080) ? wsK[btn * WSK_STRIDE + idx] : 0.0f;
            }
            cpre = c1[bt * 64 + ((tid - 256) >> 2)];
        }

        if (tid < 256) {
            const int j = tid >> 3, q = tid & 7;
            float4 k0 = *(const float4*)&sm[kfC + j * 68 + 8 * q];
            float4 k1 = *(const float4*)&sm[kfC + j * 68 + 8 * q + 4];
            float4 x0 = *(const float4*)&sm[xbC + 8 * q];
            float4 x1 = *(const float4*)&sm[xbC + 8 * q + 4];
            float pa = dot4(k0, x0) + dot4(k1, x1);
            pa += __shfl_xor(pa, 1);
            pa += __shfl_xor(pa, 2);
            pa += __shfl_xor(pa, 4);
            if (q == 0) {
                float u = pa + sm[kfC + j * 68 + 64];
                sm[UBO + j] = u;
                out[bt * 96 + 64 + j] = u;
            }
        } else {
            const int r = (tid - 256) >> 2, q = tid & 3;
            float pa = 0.0f;
#pragma unroll
            for (int e4 = 0; e4 < 4; ++e4) {
                float4 av = *(const float4*)&sm[abC + r * 100 + 16 * q + 4 * e4];
                float4 xv = *(const float4*)&sm[xbC + 16 * q + 4 * e4];
                pa += dot4(av, xv);
            }
            pa += __shfl_xor(pa, 1);
            pa += __shfl_xor(pa, 2);
            if (q == 0) sm[AXO + r] = pa + cpre;
            if (q == 1) out[bt * 96 + r] = sm[xbC + r];
        }
        __syncthreads();

        if (tid < 256) {
            const int r = tid >> 2, q = tid & 3;
            float4 b0 = *(const float4*)&sm[abC + r * 100 + 64 + 8 * q];
            float4 b1 = *(const float4*)&sm[abC + r * 100 + 64 + 8 * q + 4];
            float4 u0 = *(const float4*)&sm[UBO + 8 * q];
            float4 u1 = *(const float4*)&sm[UBO + 8 * q + 4];
            float pa = dot4(b0, u0) + dot4(b1, u1);
            pa += __shfl_xor(pa, 1);
            pa += __shfl_xor(pa, 2);
            if (q == 0) sm[xbN + r] = sm[AXO + r] + pa;
        } else {
            const int t2 = tid - 256;
#pragma unroll
            for (int it = 0; it < 6; ++it) {
                int q = t2 + 256 * it, row = q / 24, g = q % 24;
                *(float4*)&sm[abN + row * 100 + 4 * g] = abpre[it];
            }
#pragma unroll
            for (int i = 0; i < 9; ++i) {
                int idx = t2 + 256 * i;
                if (idx < 2080) {
                    int j = idx / 65, c = idx - 65 * j;
                    sm[kfN + j * 68 + c] = kpre[i];
                }
            }
        }
        __syncthreads();
    }
}

extern "C" void kernel_launch(void* const* d_in, const int* in_sizes, int n_in,
                              void* d_out, int out_size, void* d_ws, size_t ws_size,
                              hipStream_t stream) {
    (void)in_sizes; (void)n_in; (void)out_size;
    const float* Q  = (const float*)d_in[0];
    const float* p  = (const float*)d_in[1];
    const float* A  = (const float*)d_in[2];
    const float* B  = (const float*)d_in[3];
    const float* c1 = (const float*)d_in[4];
    const float* xi = (const float*)d_in[5];
    if (ws_size < (size_t)NB * TT * WSK_STRIDE * sizeof(float)) return;
    lqr_kernel<<<NB, 512, 0, stream>>>(Q, p, A, B, c1, xi, (float*)d_out, (float*)d_ws);
}

// Round 8
// 10605.286 us; speedup vs baseline: 1.1128x; 1.0636x over previous
//
#include <hip/hip_runtime.h>
#include <math.h>

#define TT 512
#define NB 16

// ---------------- LDS byte offsets (backward) ----------------
#define QH_B   0        // QH  [96][100] f32 (col 96 = qh)
#define LI_B   38400    // LI  [32][36]  f32
#define T1_B   43008    // T1T [65][36]  f32  (row 64 = qu-solve)
#define VBH_B  52368    // Vbf-hi [64][72] us
#define VBL_B  61584    // Vbf-lo
#define FTH_B  70800    // FTbf-hi [96][72] us   FT[c][k] = F[k][c]
#define FTL_B  84624
#define WTH_B  98448    // WTbf-hi [96][72] us   WT[c][i] = W[i][c]
#define WTL_B  112272
#define XUH_B  126096   // QXUbf-hi [64][40] us  XU[xrow][ucol]
#define XUL_B  131216
#define KTH_B  136336   // KTbf-hi [64][40] us   KT[c][j] = K[j][c]
#define KTL_B  141456
#define QHF_B  146576   // qhF [96] f32
#define VV_B   146960   // v [64] f32
#define CV_B   147216   // c [64] f32
#define KV_B   147472   // k [32] f32
#define SMB    147600

// ---------------- forward overlay (float offsets) ----------------
#define AB0 0
#define AB1 6400
#define KF0 12800
#define KF1 14976
#define XB0 17152
#define XB1 17216
#define UBO 17280
#define AXO 17312

#define WSK_STRIDE 2080   // per (b,t): rows j: [j*65 + c], col 64 = k

typedef __attribute__((ext_vector_type(8))) short s8v;
typedef __attribute__((ext_vector_type(4))) float f4v;

__device__ __forceinline__ float lanebc(float x, int lane) {
    return __int_as_float(__builtin_amdgcn_readlane(__float_as_int(x), lane));
}
__device__ __forceinline__ float dot4(float4 a, float4 b) {
    return a.x * b.x + a.y * b.y + a.z * b.z + a.w * b.w;
}
__device__ __forceinline__ unsigned short f2bf(float x) {
    unsigned int u = __float_as_uint(x);
    u += 0x7FFFu + ((u >> 16) & 1u);           // RNE
    return (unsigned short)(u >> 16);
}
__device__ __forceinline__ float bf2f(unsigned short h) {
    return __uint_as_float(((unsigned int)h) << 16);
}
// lower-triangular 16x16 tile enumeration: T=0..20 -> (mt,nt), nt<=mt
__device__ __forceinline__ void tileMN(int T, int& mt, int& nt) {
    mt = (T >= 15) ? 5 : (T >= 10) ? 4 : (T >= 6) ? 3 : (T >= 3) ? 2 : (T >= 1) ? 1 : 0;
    nt = T - mt * (mt + 1) / 2;
}
#define MFMA(a,b,c) __builtin_amdgcn_mfma_f32_16x16x32_bf16((a),(b),(c),0,0,0)

__launch_bounds__(512, 2)
__global__ void lqr_kernel(const float* __restrict__ Q, const float* __restrict__ P,
                           const float* __restrict__ A, const float* __restrict__ B,
                           const float* __restrict__ c1, const float* __restrict__ xinit,
                           float* __restrict__ out, float* __restrict__ ws)
{
    __shared__ __align__(16) unsigned char smb[SMB];
    float*          QHf = (float*)(smb + QH_B);
    float*          LIf = (float*)(smb + LI_B);
    float*          T1f = (float*)(smb + T1_B);
    unsigned short* VBH = (unsigned short*)(smb + VBH_B);
    unsigned short* VBL = (unsigned short*)(smb + VBL_B);
    unsigned short* FTH = (unsigned short*)(smb + FTH_B);
    unsigned short* FTL = (unsigned short*)(smb + FTL_B);
    unsigned short* WTH = (unsigned short*)(smb + WTH_B);
    unsigned short* WTL = (unsigned short*)(smb + WTL_B);
    unsigned short* XUH = (unsigned short*)(smb + XUH_B);
    unsigned short* XUL = (unsigned short*)(smb + XUL_B);
    unsigned short* KTH = (unsigned short*)(smb + KTH_B);
    unsigned short* KTL = (unsigned short*)(smb + KTL_B);
    float*          QHF = (float*)(smb + QHF_B);
    float*          VVf = (float*)(smb + VV_B);
    float*          CVf = (float*)(smb + CV_B);
    float*          KVf = (float*)(smb + KV_B);

    const int tid = threadIdx.x;
    const int b   = blockIdx.x;
    const int wv  = tid >> 6;   // 0..7
    const int ln  = tid & 63;
    const int l15 = ln & 15;
    const int lq  = ln >> 4;
    float* wsK = ws;

    const int qcnt = (wv < 5) ? 3 : 2;      // Q lower tiles per wave: {wv, wv+8, wv+16}
    const int qr = ln >> 2, qc4 = ln & 3;   // Q-stage lane mapping

    // ---- prologue: issue Q loads for t=511 immediately ----
    float4 qreg[3];
    {
        const float* Qg = Q + ((size_t)b * TT + (TT - 1)) * 9216;
#pragma unroll
        for (int tt = 0; tt < 3; ++tt) if (tt < qcnt) {
            int T = wv + 8 * tt, mt, nt; tileMN(T, mt, nt);
            qreg[tt] = *(const float4*)&Qg[(16 * mt + qr) * 96 + 16 * nt + 4 * qc4];
        }
    }

    // ---------------- init: Vbf=0, v=0, stage FTbf for t=511 ----------------
    if (tid < 384) {
        const size_t bt = (size_t)b * TT + (TT - 1);
        const int kk = tid & 63, cq = tid >> 6;
#pragma unroll
        for (int q = 0; q < 4; ++q) {
            const float* src = (cq < 4) ? (A + (bt * 64 + kk) * 64 + 16 * cq + 4 * q)
                                        : (B + (bt * 64 + kk) * 32 + 16 * (cq - 4) + 4 * q);
            float4 v = *(const float4*)src;
#pragma unroll
            for (int e = 0; e < 4; ++e) {
                int col = 16 * cq + 4 * q + e;
                float x = (e == 0) ? v.x : (e == 1) ? v.y : (e == 2) ? v.z : v.w;
                unsigned short h = f2bf(x);
                FTH[col * 72 + kk] = h;
                FTL[col * 72 + kk] = f2bf(x - bf2f(h));
            }
        }
    } else {
        float* vb = (float*)VBH;   // zero Vbf hi+lo (4608 floats contiguous)
        for (int i = tid - 384; i < 4608; i += 128) vb[i] = 0.0f;
        if (tid >= 448) VVf[tid - 448] = 0.0f;
    }
    __syncthreads();

    // ================= backward Riccati recursion =================
    for (int t = TT - 1; t >= 0; --t) {
        const size_t bt  = (size_t)b * TT + t;
        const size_t btp = (size_t)b * TT + ((t > 0) ? (t - 1) : 0);

        // ---- P1-start: commit prefetched Q_t tiles; issue next Q; prefetch A/B ----
#pragma unroll
        for (int tt = 0; tt < 3; ++tt) if (tt < qcnt) {
            int T = wv + 8 * tt, mt, nt; tileMN(T, mt, nt);
            *(float4*)&QHf[(16 * mt + qr) * 100 + 16 * nt + 4 * qc4] = qreg[tt];
        }
        {
            const float* Qg = Q + btp * 9216;
#pragma unroll
            for (int tt = 0; tt < 3; ++tt) if (tt < qcnt) {
                int T = wv + 8 * tt, mt, nt; tileMN(T, mt, nt);
                qreg[tt] = *(const float4*)&Qg[(16 * mt + qr) * 96 + 16 * nt + 4 * qc4];
            }
        }
        // next-step F prefetch: waves 1-7, up to 4 float4 each (consumed in P4 staging)
        float4 fp4[4];
        if (tid >= 64) {
#pragma unroll
            for (int it = 0; it < 4; ++it) {
                int idx = (tid - 64) + 448 * it;
                if (idx < 1536) {
                    int kk = idx / 24, g = idx % 24;
                    const float* src = (g < 16) ? (A + (btp * 64 + kk) * 64 + 4 * g)
                                                : (B + (btp * 64 + kk) * 32 + 4 * (g - 16));
                    fp4[it] = *(const float4*)src;
                }
            }
        }
        if (wv == 7 && ln < 16)
            *(float4*)&CVf[4 * ln] = *(const float4*)&c1[bt * 64 + 4 * ln];
        float pv = 0.0f;
        if (ln < 48 && (ln & 3) == 0) pv = P[bt * 96 + 12 * wv + (ln >> 2)];

        // shared tile body for QH = Qstage + F^T W (used by P2a and P2b)
        auto qhTile = [&](int T) {
            int mt, nt; tileMN(T, mt, nt);
            int orow = 16 * mt + 4 * lq, ocol = 16 * nt + l15;
            const unsigned short* ah = FTH + (16 * mt + l15) * 72 + 8 * lq;
            const unsigned short* al = FTL + (16 * mt + l15) * 72 + 8 * lq;
            const unsigned short* bh = WTH + (16 * nt + l15) * 72 + 8 * lq;
            const unsigned short* bl = WTL + (16 * nt + l15) * 72 + 8 * lq;
            f4v d;
#pragma unroll
            for (int rr = 0; rr < 4; ++rr)
                d[rr] = QHf[(orow + rr) * 100 + ocol];    // C-init = staged Q
#pragma unroll
            for (int kc = 0; kc < 2; ++kc) {
                s8v Ah = *(const s8v*)(ah + 32 * kc);
                s8v Al = *(const s8v*)(al + 32 * kc);
                s8v Bh = *(const s8v*)(bh + 32 * kc);
                s8v Bl = *(const s8v*)(bl + 32 * kc);
                d = MFMA(Ah, Bh, d);
                d = MFMA(Ah, Bl, d);
                d = MFMA(Al, Bh, d);
            }
#pragma unroll
            for (int rr = 0; rr < 4; ++rr)
                QHf[(orow + rr) * 100 + ocol] = d[rr];
            if (mt > nt) {   // mirror to upper triangle
#pragma unroll
                for (int rr = 0; rr < 4; ++rr)
                    QHf[ocol * 100 + orow + rr] = d[rr];
            }
            if (mt >= 4 && nt < 4) {   // ux tile -> XU (Qxu[x][u]) bf16 pack
#pragma unroll
                for (int rr = 0; rr < 4; ++rr) {
                    float x = d[rr];
                    unsigned short h = f2bf(x);
                    XUH[ocol * 40 + (orow + rr - 64)] = h;
                    XUL[ocol * 40 + (orow + rr - 64)] = f2bf(x - bf2f(h));
                }
            }
        };

        // ---- P1: GEMM1 (WT = (VF)^T via MFMA, 24 tiles, 3/wave) + qhF = p + F^T v ----
        {
#pragma unroll
            for (int tt = 0; tt < 3; ++tt) {
                int T = wv * 3 + tt, mt = T >> 2, nt = T & 3;
                const unsigned short* ah = FTH + (16 * mt + l15) * 72 + 8 * lq;
                const unsigned short* al = FTL + (16 * mt + l15) * 72 + 8 * lq;
                const unsigned short* bh = VBH + (16 * nt + l15) * 72 + 8 * lq;
                const unsigned short* bl = VBL + (16 * nt + l15) * 72 + 8 * lq;
                f4v d = {0.0f, 0.0f, 0.0f, 0.0f};
#pragma unroll
                for (int kc = 0; kc < 2; ++kc) {
                    s8v Ah = *(const s8v*)(ah + 32 * kc);
                    s8v Al = *(const s8v*)(al + 32 * kc);
                    s8v Bh = *(const s8v*)(bh + 32 * kc);
                    s8v Bl = *(const s8v*)(bl + 32 * kc);
                    d = MFMA(Ah, Bh, d);
                    d = MFMA(Ah, Bl, d);
                    d = MFMA(Al, Bh, d);
                }
                int orow = 16 * mt + 4 * lq, ocol = 16 * nt + l15;
#pragma unroll
                for (int rr = 0; rr < 4; ++rr) {
                    float x = d[rr];
                    unsigned short h = f2bf(x);
                    WTH[(orow + rr) * 72 + ocol] = h;
                    WTL[(orow + rr) * 72 + ocol] = f2bf(x - bf2f(h));
                }
            }
            // qhF: row = 12*wv + (ln>>2), k-quarter = ln&3
            if (ln < 48) {
                int row = 12 * wv + (ln >> 2), kq = ln & 3;
                float acc = 0.0f;
                const unsigned short* fh = FTH + row * 72 + 16 * kq;
                const unsigned short* fl = FTL + row * 72 + 16 * kq;
                const float* vvp = VVf + 16 * kq;
#pragma unroll
                for (int k = 0; k < 16; ++k)
                    acc += (bf2f(fh[k]) + bf2f(fl[k])) * vvp[k];
                acc += __shfl_xor(acc, 1);
                acc += __shfl_xor(acc, 2);
                if ((ln & 3) == 0) QHF[row] = acc + pv;
            }
        }
        __syncthreads();   // B1: WT, qhF, Q-stage ready

        // ---- P2a: 8 tiles (1/wave), all 3 uu tiles first ----
        {
            int T = (wv == 0) ? 14 : (wv == 1) ? 19 : (wv == 2) ? 20 :
                    (wv == 3) ? 0  : (wv == 4) ? 1  : (wv == 5) ? 2  :
                    (wv == 6) ? 3  : 4;
            qhTile(T);
        }
        __syncthreads();   // B2a: Quu (incl. mirror) ready

        // ---- P2b: wave0 chol+Linv  ∥  waves1-6: 2 tiles  ∥  wave7: 1 tile + qh ----
        if (wv == 0) {
            const int i = ln & 31;
            float a[32];
#pragma unroll
            for (int j4 = 0; j4 < 8; ++j4) {
                float4 v = *(const float4*)&QHf[(64 + i) * 100 + 64 + 4 * j4];
                a[4 * j4] = v.x; a[4 * j4 + 1] = v.y; a[4 * j4 + 2] = v.z; a[4 * j4 + 3] = v.w;
            }
#pragma unroll
            for (int j = 0; j < 32; ++j) {
                float dj = lanebc(a[j], j);
                float rj = rsqrtf(dj);
                a[j] *= rj;
#pragma unroll
                for (int k = j + 1; k < 32; ++k)
                    a[k] -= a[j] * lanebc(a[j], k);
            }
            float y[32];
#pragma unroll
            for (int r = 0; r < 32; ++r) {
                float acc0 = (r == i) ? 1.0f : 0.0f, acc1 = 0.0f;
#pragma unroll
                for (int j = 0; j < r; ++j) {
                    float lrj = lanebc(a[j], r);
                    if (j & 1) acc1 -= lrj * y[j]; else acc0 -= lrj * y[j];
                }
                y[r] = (acc0 + acc1) * __builtin_amdgcn_rcpf(lanebc(a[r], r));
            }
            if (ln < 32) {
#pragma unroll
                for (int r = 0; r < 32; ++r) LIf[r * 36 + ln] = y[r];
            }
        } else {
            const int Ta = (wv == 1) ? 5 : (wv == 2) ? 7 : (wv == 3) ? 9 :
                           (wv == 4) ? 11 : (wv == 5) ? 13 : (wv == 6) ? 16 : 18;
            qhTile(Ta);
            if (wv <= 6) {
                const int Tb = (wv == 1) ? 6 : (wv == 2) ? 8 : (wv == 3) ? 10 :
                               (wv == 4) ? 12 : (wv == 5) ? 15 : 17;
                qhTile(Tb);
            } else {
                // wave7: qh[j] = qhF[j] + sum_i WT[j][i] c[i]
#pragma unroll
                for (int pass = 0; pass < 2; ++pass) {
                    int j = pass ? (64 + (ln & 31)) : ln;
                    if (pass && ln >= 32) break;
                    float acc = QHF[j];
                    const unsigned short* wh = WTH + j * 72;
                    const unsigned short* wl = WTL + j * 72;
#pragma unroll 4
                    for (int i = 0; i < 64; ++i)
                        acc += (bf2f(wh[i]) + bf2f(wl[i])) * CVf[i];
                    QHf[j * 100 + 96] = acc;
                }
            }
        }
        __syncthreads();   // B3: QH full, LI, qh ready

        // ---- P4: T1T = (LI @ [Qux|qu])^T (R4 layout) + stage next FTbf ----
        {
            const int c = tid & 63, rq = tid >> 6;
            f4v acc = {0.0f, 0.0f, 0.0f, 0.0f};
#pragma unroll
            for (int j4 = 0; j4 < 8; ++j4) {
                float4 qv = *(const float4*)&QHf[c * 100 + 64 + 4 * j4];  // Qux[j][c] via symmetry
#pragma unroll
                for (int rr = 0; rr < 4; ++rr) {
                    float4 li = *(const float4*)&LIf[(4 * rq + rr) * 36 + 4 * j4];
                    acc[rr] += dot4(li, qv);
                }
            }
            *(f4v*)&T1f[c * 36 + 4 * rq] = acc;
            if (tid < 32) {   // qu column
                float aq = 0.0f;
#pragma unroll 4
                for (int j = 0; j < 32; ++j)
                    aq += LIf[tid * 36 + j] * QHf[(64 + j) * 100 + 96];
                T1f[64 * 36 + tid] = aq;
            }
            // stage next-step FTbf (waves 1-7; fp4 prefetched at P1-start)
            if (tid >= 64) {
#pragma unroll
                for (int it = 0; it < 4; ++it) {
                    int idx = (tid - 64) + 448 * it;
                    if (idx < 1536) {
                        int kk = idx / 24, g = idx % 24;
                        float4 v = fp4[it];
#pragma unroll
                        for (int e = 0; e < 4; ++e) {
                            int col = 4 * g + e;
                            float x = (e == 0) ? v.x : (e == 1) ? v.y : (e == 2) ? v.z : v.w;
                            unsigned short h = f2bf(x);
                            FTH[col * 72 + kk] = h;
                            FTL[col * 72 + kk] = f2bf(x - bf2f(h));
                        }
                    }
                }
            }
        }
        __syncthreads();   // B4: T1T, next-FT ready

        // ---- P5: K = -(LI^T T1) -> KTbf + ws ; kvec (R4 exact) ----
        {
            const int c = tid & 63, jq = tid >> 6;
            f4v acc = {0.0f, 0.0f, 0.0f, 0.0f};
#pragma unroll
            for (int i4 = 0; i4 < 8; ++i4) {
                float4 tv = *(const float4*)&T1f[c * 36 + 4 * i4];
#pragma unroll
                for (int ii = 0; ii < 4; ++ii) {
                    float4 li = *(const float4*)&LIf[(4 * i4 + ii) * 36 + 4 * jq];
                    float tvi = (ii == 0) ? tv.x : (ii == 1) ? tv.y : (ii == 2) ? tv.z : tv.w;
                    acc[0] += tvi * li.x; acc[1] += tvi * li.y;
                    acc[2] += tvi * li.z; acc[3] += tvi * li.w;
                }
            }
            float* wrow = wsK + bt * WSK_STRIDE;
#pragma unroll
            for (int jj = 0; jj < 4; ++jj) {
                float kval = -acc[jj];
                unsigned short h = f2bf(kval);
                KTH[c * 40 + 4 * jq + jj] = h;
                KTL[c * 40 + 4 * jq + jj] = f2bf(kval - bf2f(h));
                wrow[(4 * jq + jj) * 65 + c] = kval;
            }
            if (tid < 32) {   // kvec
                float aq = 0.0f;
#pragma unroll 4
                for (int i = 0; i < 32; ++i)
                    aq += LIf[i * 36 + tid] * T1f[64 * 36 + i];
                KVf[tid] = -aq;
                wsK[bt * WSK_STRIDE + tid * 65 + 64] = -aq;
            }
        }
        __syncthreads();   // B5: KTbf, kvec ready

        // ---- P6: Vn = Qxx + Qxu K via MFMA (16 tiles, 2/wave) -> Vbf direct; vn ----
        {
#pragma unroll
            for (int tt = 0; tt < 2; ++tt) {
                int T = 2 * wv + tt, mt = T >> 2, nt = T & 3;
                int orow = 16 * mt + 4 * lq, ocol = 16 * nt + l15;
                f4v d;
#pragma unroll
                for (int rr = 0; rr < 4; ++rr)
                    d[rr] = QHf[(orow + rr) * 100 + ocol];
                s8v Ah = *(const s8v*)(XUH + (16 * mt + l15) * 40 + 8 * lq);
                s8v Al = *(const s8v*)(XUL + (16 * mt + l15) * 40 + 8 * lq);
                s8v Bh = *(const s8v*)(KTH + (16 * nt + l15) * 40 + 8 * lq);
                s8v Bl = *(const s8v*)(KTL + (16 * nt + l15) * 40 + 8 * lq);
                d = MFMA(Ah, Bh, d);
                d = MFMA(Ah, Bl, d);
                d = MFMA(Al, Bh, d);
#pragma unroll
                for (int rr = 0; rr < 4; ++rr) {
                    float x = d[rr];
                    unsigned short h = f2bf(x);
                    VBH[(orow + rr) * 72 + ocol] = h;
                    VBL[(orow + rr) * 72 + ocol] = f2bf(x - bf2f(h));
                }
            }
            // vn[r] = qh[r] + sum_j Qxu[r][j]*k[j]; 8 lanes per row
            {
                int r = 8 * wv + (ln >> 3), kq = ln & 7;
                float acc = 0.0f;
#pragma unroll
                for (int e = 0; e < 4; ++e) {
                    int j = 4 * kq + e;
                    acc += QHf[r * 100 + 64 + j] * KVf[j];
                }
                acc += __shfl_xor(acc, 1);
                acc += __shfl_xor(acc, 2);
                acc += __shfl_xor(acc, 4);
                if (kq == 0) VVf[r] = acc + QHf[r * 100 + 96];
            }
        }
        __syncthreads();   // Bend: V, v ready for next step
    }

    // ================= forward rollout (as R4) =================
    float* sm = (float*)smb;
    {
        const size_t bt0 = (size_t)b * TT;
#pragma unroll
        for (int it = 0; it < 3; ++it) {
            int q = tid + 512 * it, row = q / 24, g = q % 24;
            const float* src = (g < 16) ? (A + (bt0 * 64 + row) * 64 + 4 * g)
                                        : (B + (bt0 * 64 + row) * 32 + 4 * (g - 16));
            *(float4*)&sm[AB0 + row * 100 + 4 * g] = *(const float4*)src;
        }
#pragma unroll
        for (int i = 0; i < 5; ++i) {
            int idx = tid + 512 * i;
            if (idx < 2080) {
                int j = idx / 65, c = idx - 65 * j;
                sm[KF0 + j * 68 + c] = wsK[bt0 * WSK_STRIDE + idx];
            }
        }
        if (tid < 64) sm[XB0 + tid] = xinit[b * 64 + tid];
    }
    __syncthreads();

    for (int t = 0; t < TT; ++t) {
        const size_t bt  = (size_t)b * TT + t;
        const size_t btn = (size_t)b * TT + ((t < TT - 1) ? (t + 1) : t);
        const int cur = t & 1;
        const int abC = cur ? AB1 : AB0, abN = cur ? AB0 : AB1;
        const int kfC = cur ? KF1 : KF0, kfN = cur ? KF0 : KF1;
        const int xbC = cur ? XB1 : XB0, xbN = cur ? XB0 : XB1;

        float4 abpre[6];
        float kpre[9];
        float cpre = 0.0f;
        if (tid >= 256) {
            const int t2 = tid - 256;
#pragma unroll
            for (int it = 0; it < 6; ++it) {
                int q = t2 + 256 * it, row = q / 24, g = q % 24;
                const float* src = (g < 16) ? (A + (btn * 64 + row) * 64 + 4 * g)
                                            : (B + (btn * 64 + row) * 32 + 4 * (g - 16));
                abpre[it] = *(const float4*)src;
            }
#pragma unroll
            for (int i = 0; i < 9; ++i) {
                int idx = t2 + 256 * i;
                kpre[i] = (idx < 2080) ? wsK[btn * WSK_STRIDE + idx] : 0.0f;
            }
            cpre = c1[bt * 64 + ((tid - 256) >> 2)];
        }

        if (tid < 256) {
            const int j = tid >> 3, q = tid & 7;
            float4 k0 = *(const float4*)&sm[kfC + j * 68 + 8 * q];
            float4 k1 = *(const float4*)&sm[kfC + j * 68 + 8 * q + 4];
            float4 x0 = *(const float4*)&sm[xbC + 8 * q];
            float4 x1 = *(const float4*)&sm[xbC + 8 * q + 4];
            float pa = dot4(k0, x0) + dot4(k1, x1);
            pa += __shfl_xor(pa, 1);
            pa += __shfl_xor(pa, 2);
            pa += __shfl_xor(pa, 4);
            if (q == 0) {
                float u = pa + sm[kfC + j * 68 + 64];
                sm[UBO + j] = u;
                out[bt * 96 + 64 + j] = u;
            }
        } else {
            const int r = (tid - 256) >> 2, q = tid & 3;
            float pa = 0.0f;
#pragma unroll
            for (int e4 = 0; e4 < 4; ++e4) {
                float4 av = *(const float4*)&sm[abC + r * 100 + 16 * q + 4 * e4];
                float4 xv = *(const float4*)&sm[xbC + 16 * q + 4 * e4];
                pa += dot4(av, xv);
            }
            pa += __shfl_xor(pa, 1);
            pa += __shfl_xor(pa, 2);
            if (q == 0) sm[AXO + r] = pa + cpre;
            if (q == 1) out[bt * 96 + r] = sm[xbC + r];
        }
        __syncthreads();

        if (tid < 256) {
            const int r = tid >> 2, q = tid & 3;
            float4 b0 = *(const float4*)&sm[abC + r * 100 + 64 + 8 * q];
            float4 b1 = *(const float4*)&sm[abC + r * 100 + 64 + 8 * q + 4];
            float4 u0 = *(const float4*)&sm[UBO + 8 * q];
            float4 u1 = *(const float4*)&sm[UBO + 8 * q + 4];
            float pa = dot4(b0, u0) + dot4(b1, u1);
            pa += __shfl_xor(pa, 1);
            pa += __shfl_xor(pa, 2);
            if (q == 0) sm[xbN + r] = sm[AXO + r] + pa;
        } else {
            const int t2 = tid - 256;
#pragma unroll
            for (int it = 0; it < 6; ++it) {
                int q = t2 + 256 * it, row = q / 24, g = q % 24;
                *(float4*)&sm[abN + row * 100 + 4 * g] = abpre[it];
            }
#pragma unroll
            for (int i = 0; i < 9; ++i) {
                int idx = t2 + 256 * i;
                if (idx < 2080) {
                    int j = idx / 65, c = idx - 65 * j;
                    sm[kfN + j * 68 + c] = kpre[i];
                }
            }
        }
        __syncthreads();
    }
}

extern "C" void kernel_launch(void* const* d_in, const int* in_sizes, int n_in,
                              void* d_out, int out_size, void* d_ws, size_t ws_size,
                              hipStream_t stream) {
    (void)in_sizes; (void)n_in; (void)out_size;
    const float* Q  = (const float*)d_in[0];
    const float* p  = (const float*)d_in[1];
    const float* A  = (const float*)d_in[2];
    const float* B  = (const float*)d_in[3];
    const float* c1 = (const float*)d_in[4];
    const float* xi = (const float*)d_in[5];
    if (ws_size < (size_t)NB * TT * WSK_STRIDE * sizeof(float)) return;
    lqr_kernel<<<NB, 512, 0, stream>>>(Q, p, A, B, c1, xi, (float*)d_out, (float*)d_ws);
}

// Round 9
// 8775.005 us; speedup vs baseline: 1.3449x; 1.2086x over previous
//
#include <hip/hip_runtime.h>
#include <math.h>

#define TT 512
#define NB 16

// ---------------- LDS byte offsets (backward) ----------------
#define QH_B   0        // QH  [96][100] f32 (col 96 = qh)
#define LI_B   38400    // LI  [32][36]  f32
#define T1_B   43008    // T1T [65][36]  f32  (row 64 = qu-solve)
#define VBH_B  52368    // Vbf-hi [64][72] us
#define VBL_B  61584    // Vbf-lo
#define FTH_B  70800    // FTbf-hi [96][72] us   FT[c][k] = F[k][c]
#define FTL_B  84624
#define WTH_B  98448    // WTbf-hi [96][72] us   WT[c][i] = W[i][c]
#define WTL_B  112272
#define XUH_B  126096   // QXUbf-hi [64][40] us  XU[xrow][ucol]
#define XUL_B  131216
#define KTH_B  136336   // KTbf-hi [64][40] us   KT[c][j] = K[j][c]
#define KTL_B  141456
#define QHF_B  146576   // qhF [96] f32
#define VV_B   146960   // v [64] f32
#define CV_B   147216   // c [64] f32
#define KV_B   147472   // k [32] f32
#define SMB    147600

// ---------------- forward overlay (float offsets) ----------------
#define AB0 0
#define AB1 6400
#define KF0 12800
#define KF1 14976
#define XB0 17152
#define XB1 17216
#define UBO 17280
#define AXO 17312

#define WSK_STRIDE 2080   // per (b,t): rows j: [j*65 + c], col 64 = k

typedef __attribute__((ext_vector_type(8))) short s8v;
typedef __attribute__((ext_vector_type(4))) float f4v;

__device__ __forceinline__ float lanebc(float x, int lane) {
    return __int_as_float(__builtin_amdgcn_readlane(__float_as_int(x), lane));
}
__device__ __forceinline__ float dot4(float4 a, float4 b) {
    return a.x * b.x + a.y * b.y + a.z * b.z + a.w * b.w;
}
__device__ __forceinline__ unsigned short f2bf(float x) {
    unsigned int u = __float_as_uint(x);
    u += 0x7FFFu + ((u >> 16) & 1u);           // RNE
    return (unsigned short)(u >> 16);
}
__device__ __forceinline__ float bf2f(unsigned short h) {
    return __uint_as_float(((unsigned int)h) << 16);
}
// split f4v into bf16 hi + residual-lo, as two ushort4
__device__ __forceinline__ void pack4(const f4v d, ushort4* hp, ushort4* lp) {
    unsigned short h0 = f2bf(d[0]), h1 = f2bf(d[1]), h2 = f2bf(d[2]), h3 = f2bf(d[3]);
    *hp = make_ushort4(h0, h1, h2, h3);
    *lp = make_ushort4(f2bf(d[0] - bf2f(h0)), f2bf(d[1] - bf2f(h1)),
                       f2bf(d[2] - bf2f(h2)), f2bf(d[3] - bf2f(h3)));
}
// lower-triangular 16x16 tile enumeration: T=0..20 -> (mt,nt), nt<=mt
__device__ __forceinline__ void tileMN(int T, int& mt, int& nt) {
    mt = (T >= 15) ? 5 : (T >= 10) ? 4 : (T >= 6) ? 3 : (T >= 3) ? 2 : (T >= 1) ? 1 : 0;
    nt = T - mt * (mt + 1) / 2;
}
#define MFMA(a,b,c) __builtin_amdgcn_mfma_f32_16x16x32_bf16((a),(b),(c),0,0,0)

__launch_bounds__(512, 2)
__global__ void lqr_kernel(const float* __restrict__ Q, const float* __restrict__ P,
                           const float* __restrict__ A, const float* __restrict__ B,
                           const float* __restrict__ c1, const float* __restrict__ xinit,
                           float* __restrict__ out, float* __restrict__ ws)
{
    __shared__ __align__(16) unsigned char smb[SMB];
    float*          QHf = (float*)(smb + QH_B);
    float*          LIf = (float*)(smb + LI_B);
    float*          T1f = (float*)(smb + T1_B);
    unsigned short* VBH = (unsigned short*)(smb + VBH_B);
    unsigned short* VBL = (unsigned short*)(smb + VBL_B);
    unsigned short* FTH = (unsigned short*)(smb + FTH_B);
    unsigned short* FTL = (unsigned short*)(smb + FTL_B);
    unsigned short* WTH = (unsigned short*)(smb + WTH_B);
    unsigned short* WTL = (unsigned short*)(smb + WTL_B);
    unsigned short* XUH = (unsigned short*)(smb + XUH_B);
    unsigned short* XUL = (unsigned short*)(smb + XUL_B);
    unsigned short* KTH = (unsigned short*)(smb + KTH_B);
    unsigned short* KTL = (unsigned short*)(smb + KTL_B);
    float*          QHF = (float*)(smb + QHF_B);
    float*          VVf = (float*)(smb + VV_B);
    float*          CVf = (float*)(smb + CV_B);
    float*          KVf = (float*)(smb + KV_B);

    const int tid = threadIdx.x;
    const int b   = blockIdx.x;
    const int wv  = tid >> 6;   // 0..7
    const int ln  = tid & 63;
    const int l15 = ln & 15;
    const int lq  = ln >> 4;
    float* wsK = ws;

    const int qcnt = (wv < 5) ? 3 : 2;      // Q lower tiles per wave: {wv, wv+8, wv+16}
    const int qr = ln >> 2, qc4 = ln & 3;   // Q-stage lane mapping

    // F staging 4x4-block mapping (384 threads): rb = row-block 0..15, cb = col-block 0..23
    // thread loads rows 4rb..4rb+3 x cols 4cb..4cb+3, transposes in regs, writes ushort4 per col.

    // ---- prologue: issue Q loads for t=511 immediately ----
    float4 qreg[3];
    {
        const float* Qg = Q + ((size_t)b * TT + (TT - 1)) * 9216;
#pragma unroll
        for (int tt = 0; tt < 3; ++tt) if (tt < qcnt) {
            int T = wv + 8 * tt, mt, nt; tileMN(T, mt, nt);
            qreg[tt] = *(const float4*)&Qg[(16 * mt + qr) * 96 + 16 * nt + 4 * qc4];
        }
    }

    // ---------------- init: Vbf=0, v=0, stage FTbf for t=511 ----------------
    if (tid < 384) {
        const size_t bt = (size_t)b * TT + (TT - 1);
        const int rb = tid & 15, cb = tid >> 4;
        float4 fr[4];
#pragma unroll
        for (int r = 0; r < 4; ++r) {
            const float* src = (cb < 16) ? (A + (bt * 64 + 4 * rb + r) * 64 + 4 * cb)
                                         : (B + (bt * 64 + 4 * rb + r) * 32 + 4 * (cb - 16));
            fr[r] = *(const float4*)src;
        }
#pragma unroll
        for (int c2 = 0; c2 < 4; ++c2) {
            f4v col;
            col[0] = ((const float*)&fr[0])[c2]; col[1] = ((const float*)&fr[1])[c2];
            col[2] = ((const float*)&fr[2])[c2]; col[3] = ((const float*)&fr[3])[c2];
            ushort4 hv, lv; pack4(col, &hv, &lv);
            *(ushort4*)&FTH[(4 * cb + c2) * 72 + 4 * rb] = hv;
            *(ushort4*)&FTL[(4 * cb + c2) * 72 + 4 * rb] = lv;
        }
    } else {
        float* vb = (float*)VBH;   // zero Vbf hi+lo (4608 floats contiguous)
        for (int i = tid - 384; i < 4608; i += 128) vb[i] = 0.0f;
        if (tid >= 448) VVf[tid - 448] = 0.0f;
    }
    __syncthreads();

    // ================= backward Riccati recursion =================
    for (int t = TT - 1; t >= 0; --t) {
        const size_t bt  = (size_t)b * TT + t;
        const size_t btp = (size_t)b * TT + ((t > 0) ? (t - 1) : 0);

        // ---- P1-start: commit prefetched Q_t tiles; issue next Q; prefetch A/B ----
#pragma unroll
        for (int tt = 0; tt < 3; ++tt) if (tt < qcnt) {
            int T = wv + 8 * tt, mt, nt; tileMN(T, mt, nt);
            *(float4*)&QHf[(16 * mt + qr) * 100 + 16 * nt + 4 * qc4] = qreg[tt];
        }
        {
            const float* Qg = Q + btp * 9216;
#pragma unroll
            for (int tt = 0; tt < 3; ++tt) if (tt < qcnt) {
                int T = wv + 8 * tt, mt, nt; tileMN(T, mt, nt);
                qreg[tt] = *(const float4*)&Qg[(16 * mt + qr) * 96 + 16 * nt + 4 * qc4];
            }
        }
        // next-step F prefetch (waves 1-6 = 384 threads; consumed at P3 staging)
        float4 fp4[4];
        if (wv >= 1 && wv <= 6) {
            const int tau = tid - 64, rb = tau & 15, cb = tau >> 4;
#pragma unroll
            for (int r = 0; r < 4; ++r) {
                const float* src = (cb < 16) ? (A + (btp * 64 + 4 * rb + r) * 64 + 4 * cb)
                                             : (B + (btp * 64 + 4 * rb + r) * 32 + 4 * (cb - 16));
                fp4[r] = *(const float4*)src;
            }
        }
        if (wv == 7 && ln < 16)
            *(float4*)&CVf[4 * ln] = *(const float4*)&c1[bt * 64 + 4 * ln];
        float pv = 0.0f;
        if (ln < 48 && (ln & 3) == 0) pv = P[bt * 96 + 12 * wv + (ln >> 2)];

        // ---- P1: GEMM1 W = V F via MFMA (24 tiles, 3/wave; operand-swapped so the
        //      D-fragment is [i][c] -> WT[c][i] pack is ushort4-contiguous) + qhF ----
        {
#pragma unroll
            for (int tt = 0; tt < 3; ++tt) {
                int T = wv * 3 + tt, mt = T >> 2, nt = T & 3;   // mt: c-block 0..5, nt: i-block 0..3
                const unsigned short* ah = VBH + (16 * nt + l15) * 72 + 8 * lq;   // V rows i
                const unsigned short* al = VBL + (16 * nt + l15) * 72 + 8 * lq;
                const unsigned short* bh = FTH + (16 * mt + l15) * 72 + 8 * lq;   // F^T rows c
                const unsigned short* bl = FTL + (16 * mt + l15) * 72 + 8 * lq;
                f4v d = {0.0f, 0.0f, 0.0f, 0.0f};
#pragma unroll
                for (int kc = 0; kc < 2; ++kc) {
                    s8v Ah = *(const s8v*)(ah + 32 * kc);
                    s8v Al = *(const s8v*)(al + 32 * kc);
                    s8v Bh = *(const s8v*)(bh + 32 * kc);
                    s8v Bl = *(const s8v*)(bl + 32 * kc);
                    d = MFMA(Ah, Bh, d);
                    d = MFMA(Ah, Bl, d);
                    d = MFMA(Al, Bh, d);
                }
                int wi = 16 * nt + 4 * lq, wc = 16 * mt + l15;   // D rows = i, col = c
                ushort4 hv, lv; pack4(d, &hv, &lv);
                *(ushort4*)&WTH[wc * 72 + wi] = hv;
                *(ushort4*)&WTL[wc * 72 + wi] = lv;
            }
            // qhF: row = 12*wv + (ln>>2), k-quarter = ln&3
            if (ln < 48) {
                int row = 12 * wv + (ln >> 2), kq = ln & 3;
                float acc = 0.0f;
                const unsigned short* fh = FTH + row * 72 + 16 * kq;
                const unsigned short* fl = FTL + row * 72 + 16 * kq;
                const float* vvp = VVf + 16 * kq;
#pragma unroll
                for (int k = 0; k < 16; ++k)
                    acc += (bf2f(fh[k]) + bf2f(fl[k])) * vvp[k];
                acc += __shfl_xor(acc, 1);
                acc += __shfl_xor(acc, 2);
                if ((ln & 3) == 0) QHF[row] = acc + pv;
            }
        }
        __syncthreads();   // B1: WT, qhF, Q-stage ready

        // ---- P2: QH lower tiles = Qstage + F^T W via MFMA; mirror; XU pack ----
        {
#pragma unroll
            for (int tt = 0; tt < 3; ++tt) if (tt < qcnt) {
                int T = wv + 8 * tt, mt, nt; tileMN(T, mt, nt);
                int orow = 16 * mt + 4 * lq, ocol = 16 * nt + l15;
                const unsigned short* ah = FTH + (16 * mt + l15) * 72 + 8 * lq;
                const unsigned short* al = FTL + (16 * mt + l15) * 72 + 8 * lq;
                const unsigned short* bh = WTH + (16 * nt + l15) * 72 + 8 * lq;
                const unsigned short* bl = WTL + (16 * nt + l15) * 72 + 8 * lq;
                f4v d;
#pragma unroll
                for (int rr = 0; rr < 4; ++rr)
                    d[rr] = QHf[(orow + rr) * 100 + ocol];    // C-init = staged Q
#pragma unroll
                for (int kc = 0; kc < 2; ++kc) {
                    s8v Ah = *(const s8v*)(ah + 32 * kc);
                    s8v Al = *(const s8v*)(al + 32 * kc);
                    s8v Bh = *(const s8v*)(bh + 32 * kc);
                    s8v Bl = *(const s8v*)(bl + 32 * kc);
                    d = MFMA(Ah, Bh, d);
                    d = MFMA(Ah, Bl, d);
                    d = MFMA(Al, Bh, d);
                }
#pragma unroll
                for (int rr = 0; rr < 4; ++rr)
                    QHf[(orow + rr) * 100 + ocol] = d[rr];
                if (mt > nt) {   // mirror to upper triangle
#pragma unroll
                    for (int rr = 0; rr < 4; ++rr)
                        QHf[ocol * 100 + orow + rr] = d[rr];
                }
                if (mt >= 4 && nt < 4) {   // ux tile -> XU (Qxu[x][u]) bf16 pack, contiguous
                    ushort4 hx, lx; pack4(d, &hx, &lx);
                    *(ushort4*)&XUH[ocol * 40 + (orow - 64)] = hx;
                    *(ushort4*)&XUL[ocol * 40 + (orow - 64)] = lx;
                }
            }
        }
        __syncthreads();   // B2: QH (full, mirrored) ready

        // ---- P3: wave0 chol+Linv ; wave7 qh ; waves1-6 stage next FTbf ----
        if (wv == 0) {
            const int i = ln & 31;
            float a[32];
#pragma unroll
            for (int j4 = 0; j4 < 8; ++j4) {
                float4 v = *(const float4*)&QHf[(64 + i) * 100 + 64 + 4 * j4];
                a[4 * j4] = v.x; a[4 * j4 + 1] = v.y; a[4 * j4 + 2] = v.z; a[4 * j4 + 3] = v.w;
            }
#pragma unroll
            for (int j = 0; j < 32; ++j) {
                float dj = lanebc(a[j], j);
                float rj = rsqrtf(dj);
                a[j] *= rj;
#pragma unroll
                for (int k = j + 1; k < 32; ++k)
                    a[k] -= a[j] * lanebc(a[j], k);
            }
            float y[32];
#pragma unroll
            for (int r = 0; r < 32; ++r) {
                float acc0 = (r == i) ? 1.0f : 0.0f, acc1 = 0.0f;
#pragma unroll
                for (int j = 0; j < r; ++j) {
                    float lrj = lanebc(a[j], r);
                    if (j & 1) acc1 -= lrj * y[j]; else acc0 -= lrj * y[j];
                }
                y[r] = (acc0 + acc1) * __builtin_amdgcn_rcpf(lanebc(a[r], r));
            }
            if (ln < 32) {
#pragma unroll
                for (int r = 0; r < 32; ++r) LIf[r * 36 + ln] = y[r];
            }
        } else if (wv == 7) {
            // qh[j] = qhF[j] + sum_i WT[j][i] c[i]
#pragma unroll
            for (int pass = 0; pass < 2; ++pass) {
                int j = pass ? (64 + (ln & 31)) : ln;
                if (pass && ln >= 32) break;
                float acc = QHF[j];
                const unsigned short* wh = WTH + j * 72;
                const unsigned short* wl = WTL + j * 72;
#pragma unroll 4
                for (int i = 0; i < 64; ++i)
                    acc += (bf2f(wh[i]) + bf2f(wl[i])) * CVf[i];
                QHf[j * 100 + 96] = acc;
            }
        } else {
            // stage next-step FTbf from fp4 (4x4 register transpose, ushort4 writes)
            const int tau = tid - 64, rb = tau & 15, cb = tau >> 4;
#pragma unroll
            for (int c2 = 0; c2 < 4; ++c2) {
                f4v col;
                col[0] = ((const float*)&fp4[0])[c2]; col[1] = ((const float*)&fp4[1])[c2];
                col[2] = ((const float*)&fp4[2])[c2]; col[3] = ((const float*)&fp4[3])[c2];
                ushort4 hv, lv; pack4(col, &hv, &lv);
                *(ushort4*)&FTH[(4 * cb + c2) * 72 + 4 * rb] = hv;
                *(ushort4*)&FTL[(4 * cb + c2) * 72 + 4 * rb] = lv;
            }
        }
        __syncthreads();   // B3: LI, qh, next-FT ready

        // ---- P4: T1T = (LI @ [Qux|qu])^T, all waves ----
        {
            const int c = tid & 63, rq = tid >> 6;
            f4v acc = {0.0f, 0.0f, 0.0f, 0.0f};
#pragma unroll
            for (int j4 = 0; j4 < 8; ++j4) {
                float4 qv = *(const float4*)&QHf[c * 100 + 64 + 4 * j4];  // Qux[j][c] via symmetry
#pragma unroll
                for (int rr = 0; rr < 4; ++rr) {
                    float4 li = *(const float4*)&LIf[(4 * rq + rr) * 36 + 4 * j4];
                    acc[rr] += dot4(li, qv);
                }
            }
            *(f4v*)&T1f[c * 36 + 4 * rq] = acc;
            if (tid < 32) {   // qu column
                float aq = 0.0f;
#pragma unroll 4
                for (int j = 0; j < 32; ++j)
                    aq += LIf[tid * 36 + j] * QHf[(64 + j) * 100 + 96];
                T1f[64 * 36 + tid] = aq;
            }
        }
        __syncthreads();   // B4: T1T ready

        // ---- P5: K = -(LI^T T1) -> KTbf + ws ; kvec ----
        {
            const int c = tid & 63, jq = tid >> 6;
            f4v acc = {0.0f, 0.0f, 0.0f, 0.0f};
#pragma unroll
            for (int i4 = 0; i4 < 8; ++i4) {
                float4 tv = *(const float4*)&T1f[c * 36 + 4 * i4];
#pragma unroll
                for (int ii = 0; ii < 4; ++ii) {
                    float4 li = *(const float4*)&LIf[(4 * i4 + ii) * 36 + 4 * jq];
                    float tvi = (ii == 0) ? tv.x : (ii == 1) ? tv.y : (ii == 2) ? tv.z : tv.w;
                    acc[0] += tvi * li.x; acc[1] += tvi * li.y;
                    acc[2] += tvi * li.z; acc[3] += tvi * li.w;
                }
            }
            f4v kv; kv[0] = -acc[0]; kv[1] = -acc[1]; kv[2] = -acc[2]; kv[3] = -acc[3];
            ushort4 hk, lk; pack4(kv, &hk, &lk);
            *(ushort4*)&KTH[c * 40 + 4 * jq] = hk;
            *(ushort4*)&KTL[c * 40 + 4 * jq] = lk;
            float* wrow = wsK + bt * WSK_STRIDE;
#pragma unroll
            for (int jj = 0; jj < 4; ++jj)
                wrow[(4 * jq + jj) * 65 + c] = kv[jj];
            if (tid < 32) {   // kvec
                float aq = 0.0f;
#pragma unroll 4
                for (int i = 0; i < 32; ++i)
                    aq += LIf[i * 36 + tid] * T1f[64 * 36 + i];
                KVf[tid] = -aq;
                wsK[bt * WSK_STRIDE + tid * 65 + 64] = -aq;
            }
        }
        __syncthreads();   // B5: KTbf, kvec ready

        // ---- P6: Vn = Qxx + Qxu K via MFMA (16 tiles, 2/wave; operand-swapped so the
        //      Vbf pack is ushort4-contiguous); vn ----
        {
#pragma unroll
            for (int tt = 0; tt < 2; ++tt) {
                int T = 2 * wv + tt, mt = T >> 2, nt = T & 3;   // mt: x1-block, nt: x2-block
                f4v d;
#pragma unroll
                for (int rr = 0; rr < 4; ++rr)
                    d[rr] = QHf[(16 * nt + 4 * lq + rr) * 100 + 16 * mt + l15];   // Qxx[x2][x1]
                s8v Ah = *(const s8v*)(KTH + (16 * nt + l15) * 40 + 8 * lq);   // K^T rows x2
                s8v Al = *(const s8v*)(KTL + (16 * nt + l15) * 40 + 8 * lq);
                s8v Bh = *(const s8v*)(XUH + (16 * mt + l15) * 40 + 8 * lq);   // Qxu rows x1
                s8v Bl = *(const s8v*)(XUL + (16 * mt + l15) * 40 + 8 * lq);
                d = MFMA(Ah, Bh, d);
                d = MFMA(Ah, Bl, d);
                d = MFMA(Al, Bh, d);
                // D rows = x2, col = x1 -> write VB[x1][x2..x2+3] contiguous
                ushort4 hv, lv; pack4(d, &hv, &lv);
                *(ushort4*)&VBH[(16 * mt + l15) * 72 + 16 * nt + 4 * lq] = hv;
                *(ushort4*)&VBL[(16 * mt + l15) * 72 + 16 * nt + 4 * lq] = lv;
            }
            // vn[r] = qh[r] + sum_j Qxu[r][j]*k[j]; 8 lanes per row
            {
                int r = 8 * wv + (ln >> 3), kq = ln & 7;
                float acc = 0.0f;
#pragma unroll
                for (int e = 0; e < 4; ++e) {
                    int j = 4 * kq + e;
                    acc += QHf[r * 100 + 64 + j] * KVf[j];
                }
                acc += __shfl_xor(acc, 1);
                acc += __shfl_xor(acc, 2);
                acc += __shfl_xor(acc, 4);
                if (kq == 0) VVf[r] = acc + QHf[r * 100 + 96];
            }
        }
        __syncthreads();   // Bend: V, v ready for next step
    }

    // ================= forward rollout (as R4) =================
    float* sm = (float*)smb;
    {
        const size_t bt0 = (size_t)b * TT;
#pragma unroll
        for (int it = 0; it < 3; ++it) {
            int q = tid + 512 * it, row = q / 24, g = q % 24;
            const float* src = (g < 16) ? (A + (bt0 * 64 + row) * 64 + 4 * g)
                                        : (B + (bt0 * 64 + row) * 32 + 4 * (g - 16));
            *(float4*)&sm[AB0 + row * 100 + 4 * g] = *(const float4*)src;
        }
#pragma unroll
        for (int i = 0; i < 5; ++i) {
            int idx = tid + 512 * i;
            if (idx < 2080) {
                int j = idx / 65, c = idx - 65 * j;
                sm[KF0 + j * 68 + c] = wsK[bt0 * WSK_STRIDE + idx];
            }
        }
        if (tid < 64) sm[XB0 + tid] = xinit[b * 64 + tid];
    }
    __syncthreads();

    for (int t = 0; t < TT; ++t) {
        const size_t bt  = (size_t)b * TT + t;
        const size_t btn = (size_t)b * TT + ((t < TT - 1) ? (t + 1) : t);
        const int cur = t & 1;
        const int abC = cur ? AB1 : AB0, abN = cur ? AB0 : AB1;
        const int kfC = cur ? KF1 : KF0, kfN = cur ? KF0 : KF1;
        const int xbC = cur ? XB1 : XB0, xbN = cur ? XB0 : XB1;

        float4 abpre[6];
        float kpre[9];
        float cpre = 0.0f;
        if (tid >= 256) {
            const int t2 = tid - 256;
#pragma unroll
            for (int it = 0; it < 6; ++it) {
                int q = t2 + 256 * it, row = q / 24, g = q % 24;
                const float* src = (g < 16) ? (A + (btn * 64 + row) * 64 + 4 * g)
                                            : (B + (btn * 64 + row) * 32 + 4 * (g - 16));
                abpre[it] = *(const float4*)src;
            }
#pragma unroll
            for (int i = 0; i < 9; ++i) {
                int idx = t2 + 256 * i;
                kpre[i] = (idx < 2080) ? wsK[btn * WSK_STRIDE + idx] : 0.0f;
            }
            cpre = c1[bt * 64 + ((tid - 256) >> 2)];
        }

        if (tid < 256) {
            const int j = tid >> 3, q = tid & 7;
            float4 k0 = *(const float4*)&sm[kfC + j * 68 + 8 * q];
            float4 k1 = *(const float4*)&sm[kfC + j * 68 + 8 * q + 4];
            float4 x0 = *(const float4*)&sm[xbC + 8 * q];
            float4 x1 = *(const float4*)&sm[xbC + 8 * q + 4];
            float pa = dot4(k0, x0) + dot4(k1, x1);
            pa += __shfl_xor(pa, 1);
            pa += __shfl_xor(pa, 2);
            pa += __shfl_xor(pa, 4);
            if (q == 0) {
                float u = pa + sm[kfC + j * 68 + 64];
                sm[UBO + j] = u;
                out[bt * 96 + 64 + j] = u;
            }
        } else {
            const int r = (tid - 256) >> 2, q = tid & 3;
            float pa = 0.0f;
#pragma unroll
            for (int e4 = 0; e4 < 4; ++e4) {
                float4 av = *(const float4*)&sm[abC + r * 100 + 16 * q + 4 * e4];
                float4 xv = *(const float4*)&sm[xbC + 16 * q + 4 * e4];
                pa += dot4(av, xv);
            }
            pa += __shfl_xor(pa, 1);
            pa += __shfl_xor(pa, 2);
            if (q == 0) sm[AXO + r] = pa + cpre;
            if (q == 1) out[bt * 96 + r] = sm[xbC + r];
        }
        __syncthreads();

        if (tid < 256) {
            const int r = tid >> 2, q = tid & 3;
            float4 b0 = *(const float4*)&sm[abC + r * 100 + 64 + 8 * q];
            float4 b1 = *(const float4*)&sm[abC + r * 100 + 64 + 8 * q + 4];
            float4 u0 = *(const float4*)&sm[UBO + 8 * q];
            float4 u1 = *(const float4*)&sm[UBO + 8 * q + 4];
            float pa = dot4(b0, u0) + dot4(b1, u1);
            pa += __shfl_xor(pa, 1);
            pa += __shfl_xor(pa, 2);
            if (q == 0) sm[xbN + r] = sm[AXO + r] + pa;
        } else {
            const int t2 = tid - 256;
#pragma unroll
            for (int it = 0; it < 6; ++it) {
                int q = t2 + 256 * it, row = q / 24, g = q % 24;
                *(float4*)&sm[abN + row * 100 + 4 * g] = abpre[it];
            }
#pragma unroll
            for (int i = 0; i < 9; ++i) {
                int idx = t2 + 256 * i;
                if (idx < 2080) {
                    int j = idx / 65, c = idx - 65 * j;
                    sm[kfN + j * 68 + c] = kpre[i];
                }
            }
        }
        __syncthreads();
    }
}

extern "C" void kernel_launch(void* const* d_in, const int* in_sizes, int n_in,
                              void* d_out, int out_size, void* d_ws, size_t ws_size,
                              hipStream_t stream) {
    (void)in_sizes; (void)n_in; (void)out_size;
    const float* Q  = (const float*)d_in[0];
    const float* p  = (const float*)d_in[1];
    const float* A  = (const float*)d_in[2];
    const float* B  = (const float*)d_in[3];
    const float* c1 = (const float*)d_in[4];
    const float* xi = (const float*)d_in[5];
    if (ws_size < (size_t)NB * TT * WSK_STRIDE * sizeof(float)) return;
    lqr_kernel<<<NB, 512, 0, stream>>>(Q, p, A, B, c1, xi, (float*)d_out, (float*)d_ws);
}

// Round 11
// 8755.708 us; speedup vs baseline: 1.3478x; 1.0022x over previous
//
#include <hip/hip_runtime.h>
#include <math.h>

#define TT 512
#define NB 16

// ---------------- LDS byte offsets (backward) ----------------
#define QH_B   0        // QH  [96][100] f32 (col 96 = qh)
#define LI_B   38400    // LI  [32][36]  f32
#define T1_B   43008    // T1T [65][36]  f32  (row 64 = qu-solve)
#define VBH_B  52368    // Vbf-hi [64][72] us
#define VBL_B  61584    // Vbf-lo
#define FTH_B  70800    // FTbf-hi [96][72] us   FT[c][k] = F[k][c]
#define FTL_B  84624
#define WTH_B  98448    // WTbf-hi [96][72] us   WT[c][i] = W[i][c]
#define WTL_B  112272
#define XUH_B  126096   // QXUbf-hi [64][40] us  XU[xrow][ucol]
#define XUL_B  131216
#define KTH_B  136336   // KTbf-hi [64][40] us   KT[c][j] = K[j][c]
#define KTL_B  141456
#define QHF_B  146576   // qhF [96] f32
#define VV_B   146960   // v [64] f32
#define CV_B   147216   // c [64] f32
#define KV_B   147472   // k [32] f32
#define SMB    147600

// ---------------- forward overlay (float offsets) ----------------
#define AB0 0
#define AB1 6400
#define KF0 12800
#define KF1 14976
#define XB0 17152
#define XB1 17216
#define UBO 17280
#define AXO 17312

#define WSK_STRIDE 2080   // per (b,t): rows j: [j*65 + c], col 64 = k

typedef __attribute__((ext_vector_type(8))) short s8v;
typedef __attribute__((ext_vector_type(4))) float f4v;

__device__ __forceinline__ float lanebc(float x, int lane) {
    return __int_as_float(__builtin_amdgcn_readlane(__float_as_int(x), lane));
}
__device__ __forceinline__ float dot4(float4 a, float4 b) {
    return a.x * b.x + a.y * b.y + a.z * b.z + a.w * b.w;
}
__device__ __forceinline__ unsigned short f2bf(float x) {
    unsigned int u = __float_as_uint(x);
    u += 0x7FFFu + ((u >> 16) & 1u);           // RNE
    return (unsigned short)(u >> 16);
}
__device__ __forceinline__ float bf2f(unsigned short h) {
    return __uint_as_float(((unsigned int)h) << 16);
}
// split f4v into bf16 hi + residual-lo, as two ushort4
__device__ __forceinline__ void pack4(const f4v d, ushort4* hp, ushort4* lp) {
    unsigned short h0 = f2bf(d[0]), h1 = f2bf(d[1]), h2 = f2bf(d[2]), h3 = f2bf(d[3]);
    *hp = make_ushort4(h0, h1, h2, h3);
    *lp = make_ushort4(f2bf(d[0] - bf2f(h0)), f2bf(d[1] - bf2f(h1)),
                       f2bf(d[2] - bf2f(h2)), f2bf(d[3] - bf2f(h3)));
}
// lower-triangular 16x16 tile enumeration: T=0..20 -> (mt,nt), nt<=mt
__device__ __forceinline__ void tileMN(int T, int& mt, int& nt) {
    mt = (T >= 15) ? 5 : (T >= 10) ? 4 : (T >= 6) ? 3 : (T >= 3) ? 2 : (T >= 1) ? 1 : 0;
    nt = T - mt * (mt + 1) / 2;
}
#define MFMA(a,b,c) __builtin_amdgcn_mfma_f32_16x16x32_bf16((a),(b),(c),0,0,0)

__launch_bounds__(512, 2)
__global__ void lqr_kernel(const float* __restrict__ Q, const float* __restrict__ P,
                           const float* __restrict__ A, const float* __restrict__ B,
                           const float* __restrict__ c1, const float* __restrict__ xinit,
                           float* __restrict__ out, float* __restrict__ ws)
{
    __shared__ __align__(16) unsigned char smb[SMB];
    float*          QHf = (float*)(smb + QH_B);
    float*          LIf = (float*)(smb + LI_B);
    float*          T1f = (float*)(smb + T1_B);
    unsigned short* VBH = (unsigned short*)(smb + VBH_B);
    unsigned short* VBL = (unsigned short*)(smb + VBL_B);
    unsigned short* FTH = (unsigned short*)(smb + FTH_B);
    unsigned short* FTL = (unsigned short*)(smb + FTL_B);
    unsigned short* WTH = (unsigned short*)(smb + WTH_B);
    unsigned short* WTL = (unsigned short*)(smb + WTL_B);
    unsigned short* XUH = (unsigned short*)(smb + XUH_B);
    unsigned short* XUL = (unsigned short*)(smb + XUL_B);
    unsigned short* KTH = (unsigned short*)(smb + KTH_B);
    unsigned short* KTL = (unsigned short*)(smb + KTL_B);
    float*          QHF = (float*)(smb + QHF_B);
    float*          VVf = (float*)(smb + VV_B);
    float*          CVf = (float*)(smb + CV_B);
    float*          KVf = (float*)(smb + KV_B);

    const int tid = threadIdx.x;
    const int b   = blockIdx.x;
    const int wv  = tid >> 6;   // 0..7
    const int ln  = tid & 63;
    const int l15 = ln & 15;
    const int lq  = ln >> 4;
    float* wsK = ws;

    const int qcnt = (wv < 5) ? 3 : 2;      // Q lower tiles per wave: {wv, wv+8, wv+16}
    const int qr = ln >> 2, qc4 = ln & 3;   // Q-stage lane mapping

    // ---- prologue: issue Q loads for t=511 immediately ----
    float4 qreg[3];
    {
        const float* Qg = Q + ((size_t)b * TT + (TT - 1)) * 9216;
#pragma unroll
        for (int tt = 0; tt < 3; ++tt) if (tt < qcnt) {
            int T = wv + 8 * tt, mt, nt; tileMN(T, mt, nt);
            qreg[tt] = *(const float4*)&Qg[(16 * mt + qr) * 96 + 16 * nt + 4 * qc4];
        }
    }

    // ---------------- init: Vbf=0, v=0, stage FTbf for t=511 ----------------
    if (tid < 384) {
        const size_t bt = (size_t)b * TT + (TT - 1);
        const int rb = tid & 15, cb = tid >> 4;
        float4 fr[4];
#pragma unroll
        for (int r = 0; r < 4; ++r) {
            const float* src = (cb < 16) ? (A + (bt * 64 + 4 * rb + r) * 64 + 4 * cb)
                                         : (B + (bt * 64 + 4 * rb + r) * 32 + 4 * (cb - 16));
            fr[r] = *(const float4*)src;
        }
#pragma unroll
        for (int c2 = 0; c2 < 4; ++c2) {
            f4v col;
            col[0] = ((const float*)&fr[0])[c2]; col[1] = ((const float*)&fr[1])[c2];
            col[2] = ((const float*)&fr[2])[c2]; col[3] = ((const float*)&fr[3])[c2];
            ushort4 hv, lv; pack4(col, &hv, &lv);
            *(ushort4*)&FTH[(4 * cb + c2) * 72 + 4 * rb] = hv;
            *(ushort4*)&FTL[(4 * cb + c2) * 72 + 4 * rb] = lv;
        }
    } else {
        float* vb = (float*)VBH;   // zero Vbf hi+lo (4608 floats contiguous)
        for (int i = tid - 384; i < 4608; i += 128) vb[i] = 0.0f;
        if (tid >= 448) VVf[tid - 448] = 0.0f;
    }
    __syncthreads();

    // ================= backward Riccati recursion =================
    for (int t = TT - 1; t >= 0; --t) {
        const size_t bt  = (size_t)b * TT + t;
        const size_t btp = (size_t)b * TT + ((t > 0) ? (t - 1) : 0);

        // ---- P1a-start: commit prefetched Q_t tiles; issue next Q; prefetch A/B ----
#pragma unroll
        for (int tt = 0; tt < 3; ++tt) if (tt < qcnt) {
            int T = wv + 8 * tt, mt, nt; tileMN(T, mt, nt);
            *(float4*)&QHf[(16 * mt + qr) * 100 + 16 * nt + 4 * qc4] = qreg[tt];
        }
        {
            const float* Qg = Q + btp * 9216;
#pragma unroll
            for (int tt = 0; tt < 3; ++tt) if (tt < qcnt) {
                int T = wv + 8 * tt, mt, nt; tileMN(T, mt, nt);
                qreg[tt] = *(const float4*)&Qg[(16 * mt + qr) * 96 + 16 * nt + 4 * qc4];
            }
        }
        // next-step F prefetch (waves 1-6 = 384 threads; consumed at P4 staging)
        float4 fp4[4];
        if (wv >= 1 && wv <= 6) {
            const int tau = tid - 64, rb = tau & 15, cb = tau >> 4;
#pragma unroll
            for (int r = 0; r < 4; ++r) {
                const float* src = (cb < 16) ? (A + (btp * 64 + 4 * rb + r) * 64 + 4 * cb)
                                             : (B + (btp * 64 + 4 * rb + r) * 32 + 4 * (cb - 16));
                fp4[r] = *(const float4*)src;
            }
        }
        if (wv == 7 && ln < 16)
            *(float4*)&CVf[4 * ln] = *(const float4*)&c1[bt * 64 + 4 * ln];
        float pv = 0.0f;
        if (ln < 48 && (ln & 3) == 0) pv = P[bt * 96 + 12 * wv + (ln >> 2)];

        // GEMM1 tile body (operand-swapped): WT[c][i] for c-block mt (0..5), i-block nt (0..3)
        auto g1Tile = [&](int mt, int nt) {
            const unsigned short* ah = VBH + (16 * nt + l15) * 72 + 8 * lq;   // V rows i
            const unsigned short* al = VBL + (16 * nt + l15) * 72 + 8 * lq;
            const unsigned short* bh = FTH + (16 * mt + l15) * 72 + 8 * lq;   // F^T rows c
            const unsigned short* bl = FTL + (16 * mt + l15) * 72 + 8 * lq;
            f4v d = {0.0f, 0.0f, 0.0f, 0.0f};
#pragma unroll
            for (int kc = 0; kc < 2; ++kc) {
                s8v Ah = *(const s8v*)(ah + 32 * kc);
                s8v Al = *(const s8v*)(al + 32 * kc);
                s8v Bh = *(const s8v*)(bh + 32 * kc);
                s8v Bl = *(const s8v*)(bl + 32 * kc);
                d = MFMA(Ah, Bh, d);
                d = MFMA(Ah, Bl, d);
                d = MFMA(Al, Bh, d);
            }
            int wi = 16 * nt + 4 * lq, wc = 16 * mt + l15;
            ushort4 hv, lv; pack4(d, &hv, &lv);
            *(ushort4*)&WTH[wc * 72 + wi] = hv;
            *(ushort4*)&WTL[wc * 72 + wi] = lv;
        };
        // Q-hat tile body: QH = Qstage + F^T W; mirror; XU pack (lower tile T)
        auto qhTile = [&](int T) {
            int mt, nt; tileMN(T, mt, nt);
            int orow = 16 * mt + 4 * lq, ocol = 16 * nt + l15;
            const unsigned short* ah = FTH + (16 * mt + l15) * 72 + 8 * lq;
            const unsigned short* al = FTL + (16 * mt + l15) * 72 + 8 * lq;
            const unsigned short* bh = WTH + (16 * nt + l15) * 72 + 8 * lq;
            const unsigned short* bl = WTL + (16 * nt + l15) * 72 + 8 * lq;
            f4v d;
#pragma unroll
            for (int rr = 0; rr < 4; ++rr)
                d[rr] = QHf[(orow + rr) * 100 + ocol];    // C-init = staged Q
#pragma unroll
            for (int kc = 0; kc < 2; ++kc) {
                s8v Ah = *(const s8v*)(ah + 32 * kc);
                s8v Al = *(const s8v*)(al + 32 * kc);
                s8v Bh = *(const s8v*)(bh + 32 * kc);
                s8v Bl = *(const s8v*)(bl + 32 * kc);
                d = MFMA(Ah, Bh, d);
                d = MFMA(Ah, Bl, d);
                d = MFMA(Al, Bh, d);
            }
#pragma unroll
            for (int rr = 0; rr < 4; ++rr)
                QHf[(orow + rr) * 100 + ocol] = d[rr];
            if (mt > nt) {   // mirror to upper triangle
#pragma unroll
                for (int rr = 0; rr < 4; ++rr)
                    QHf[ocol * 100 + orow + rr] = d[rr];
            }
            if (mt >= 4 && nt < 4) {   // ux tile -> XU (Qxu[x][u]) bf16 pack, contiguous
                ushort4 hx, lx; pack4(d, &hx, &lx);
                *(ushort4*)&XUH[ocol * 40 + (orow - 64)] = hx;
                *(ushort4*)&XUL[ocol * 40 + (orow - 64)] = lx;
            }
        };

        // ---- P1a: WT u-row tiles (8, 1/wave) + qhF = p + F^T v ----
        {
            g1Tile(4 + (wv >> 2), wv & 3);
            if (ln < 48) {
                int row = 12 * wv + (ln >> 2), kq = ln & 3;
                float acc = 0.0f;
                const unsigned short* fh = FTH + row * 72 + 16 * kq;
                const unsigned short* fl = FTL + row * 72 + 16 * kq;
                const float* vvp = VVf + 16 * kq;
#pragma unroll
                for (int k = 0; k < 16; ++k)
                    acc += (bf2f(fh[k]) + bf2f(fl[k])) * vvp[k];
                acc += __shfl_xor(acc, 1);
                acc += __shfl_xor(acc, 2);
                if ((ln & 3) == 0) QHF[row] = acc + pv;
            }
        }
        __syncthreads();   // B1a: WT-u, qhF, Q-stage ready

        // ---- P1b: wave0: 3 uu Q-hat tiles ; waves1-7: 16 WT x-row tiles ----
        if (wv == 0) {
            qhTile(14); qhTile(19); qhTile(20);
        } else {
            int g0 = wv - 1;  g1Tile(g0 >> 2, g0 & 3);
            int g1 = 6 + wv;  g1Tile(g1 >> 2, g1 & 3);
            if (wv <= 2) { int g2 = 13 + wv; g1Tile(g2 >> 2, g2 & 3); }
        }
        __syncthreads();   // B1b: Quu + full WT ready

        // ---- P2': wave0 chol (setprio) || waves1-6: 18 Q-hat tiles || wave7 qh ----
        if (wv == 0) {
            __builtin_amdgcn_s_setprio(1);
            const int i = ln & 31;
            float a[32];
#pragma unroll
            for (int j4 = 0; j4 < 8; ++j4) {
                float4 v = *(const float4*)&QHf[(64 + i) * 100 + 64 + 4 * j4];
                a[4 * j4] = v.x; a[4 * j4 + 1] = v.y; a[4 * j4 + 2] = v.z; a[4 * j4 + 3] = v.w;
            }
#pragma unroll
            for (int j = 0; j < 32; ++j) {
                float dj = lanebc(a[j], j);
                float rj = rsqrtf(dj);
                a[j] *= rj;
#pragma unroll
                for (int k = j + 1; k < 32; ++k)
                    a[k] -= a[j] * lanebc(a[j], k);
            }
            float y[32];
#pragma unroll
            for (int r = 0; r < 32; ++r) {
                float acc0 = (r == i) ? 1.0f : 0.0f, acc1 = 0.0f;
#pragma unroll
                for (int j = 0; j < r; ++j) {
                    float lrj = lanebc(a[j], r);
                    if (j & 1) acc1 -= lrj * y[j]; else acc0 -= lrj * y[j];
                }
                y[r] = (acc0 + acc1) * __builtin_amdgcn_rcpf(lanebc(a[r], r));
            }
            __builtin_amdgcn_s_setprio(0);
            if (ln < 32) {
#pragma unroll
                for (int r = 0; r < 32; ++r) LIf[r * 36 + ln] = y[r];
            }
        } else if (wv == 7) {
            // qh[j] = qhF[j] + sum_i WT[j][i] c[i]
#pragma unroll
            for (int pass = 0; pass < 2; ++pass) {
                int j = pass ? (64 + (ln & 31)) : ln;
                if (pass && ln >= 32) break;
                float acc = QHF[j];
                const unsigned short* wh = WTH + j * 72;
                const unsigned short* wl = WTL + j * 72;
#pragma unroll 4
                for (int i = 0; i < 64; ++i)
                    acc += (bf2f(wh[i]) + bf2f(wl[i])) * CVf[i];
                QHf[j * 100 + 96] = acc;
            }
        } else {
            // 18 tiles (8 ux + 10 xx), 3 per wave — FT staging deferred to P4 (WAR-free)
            int ta, tb, tc;
            switch (wv) {
                case 1: ta = 10; tb = 15; tc = 0; break;
                case 2: ta = 11; tb = 16; tc = 1; break;
                case 3: ta = 12; tb = 17; tc = 2; break;
                case 4: ta = 13; tb = 18; tc = 3; break;
                case 5: ta = 4;  tb = 5;  tc = 6; break;
                default: ta = 7; tb = 8;  tc = 9; break;   // wv==6
            }
            qhTile(ta); qhTile(tb); qhTile(tc);
        }
        __syncthreads();   // B2': QH full, LI, qh ready

        // ---- P4: T1T = (LI @ [Qux|qu])^T, all waves ; waves1-6 stage next FTbf ----
        {
            const int c = tid & 63, rq = tid >> 6;
            f4v acc = {0.0f, 0.0f, 0.0f, 0.0f};
#pragma unroll
            for (int j4 = 0; j4 < 8; ++j4) {
                float4 qv = *(const float4*)&QHf[c * 100 + 64 + 4 * j4];  // Qux[j][c] via symmetry
#pragma unroll
                for (int rr = 0; rr < 4; ++rr) {
                    float4 li = *(const float4*)&LIf[(4 * rq + rr) * 36 + 4 * j4];
                    acc[rr] += dot4(li, qv);
                }
            }
            *(f4v*)&T1f[c * 36 + 4 * rq] = acc;
            if (tid < 32) {   // qu column
                float aq = 0.0f;
#pragma unroll 4
                for (int j = 0; j < 32; ++j)
                    aq += LIf[tid * 36 + j] * QHf[(64 + j) * 100 + 96];
                T1f[64 * 36 + tid] = aq;
            }
            // stage next-step FTbf (waves 1-6; nothing reads FT until next step's P1a)
            if (wv >= 1 && wv <= 6) {
                const int tau = tid - 64, rb = tau & 15, cb = tau >> 4;
#pragma unroll
                for (int c2 = 0; c2 < 4; ++c2) {
                    f4v col;
                    col[0] = ((const float*)&fp4[0])[c2]; col[1] = ((const float*)&fp4[1])[c2];
                    col[2] = ((const float*)&fp4[2])[c2]; col[3] = ((const float*)&fp4[3])[c2];
                    ushort4 hv, lv; pack4(col, &hv, &lv);
                    *(ushort4*)&FTH[(4 * cb + c2) * 72 + 4 * rb] = hv;
                    *(ushort4*)&FTL[(4 * cb + c2) * 72 + 4 * rb] = lv;
                }
            }
        }
        __syncthreads();   // B4: T1T, next-FT ready

        // ---- P5: K = -(LI^T T1) -> KTbf + ws ; kvec ----
        {
            const int c = tid & 63, jq = tid >> 6;
            f4v acc = {0.0f, 0.0f, 0.0f, 0.0f};
#pragma unroll
            for (int i4 = 0; i4 < 8; ++i4) {
                float4 tv = *(const float4*)&T1f[c * 36 + 4 * i4];
#pragma unroll
                for (int ii = 0; ii < 4; ++ii) {
                    float4 li = *(const float4*)&LIf[(4 * i4 + ii) * 36 + 4 * jq];
                    float tvi = (ii == 0) ? tv.x : (ii == 1) ? tv.y : (ii == 2) ? tv.z : tv.w;
                    acc[0] += tvi * li.x; acc[1] += tvi * li.y;
                    acc[2] += tvi * li.z; acc[3] += tvi * li.w;
                }
            }
            f4v kv; kv[0] = -acc[0]; kv[1] = -acc[1]; kv[2] = -acc[2]; kv[3] = -acc[3];
            ushort4 hk, lk; pack4(kv, &hk, &lk);
            *(ushort4*)&KTH[c * 40 + 4 * jq] = hk;
            *(ushort4*)&KTL[c * 40 + 4 * jq] = lk;
            float* wrow = wsK + bt * WSK_STRIDE;
#pragma unroll
            for (int jj = 0; jj < 4; ++jj)
                wrow[(4 * jq + jj) * 65 + c] = kv[jj];
            if (tid < 32) {   // kvec
                float aq = 0.0f;
#pragma unroll 4
                for (int i = 0; i < 32; ++i)
                    aq += LIf[i * 36 + tid] * T1f[64 * 36 + i];
                KVf[tid] = -aq;
                wsK[bt * WSK_STRIDE + tid * 65 + 64] = -aq;
            }
        }
        __syncthreads();   // B5: KTbf, kvec ready

        // ---- P6: Vn = Qxx + Qxu K via MFMA (16 tiles, 2/wave; swapped operands) ; vn ----
        {
#pragma unroll
            for (int tt = 0; tt < 2; ++tt) {
                int T = 2 * wv + tt, mt = T >> 2, nt = T & 3;   // mt: x1-block, nt: x2-block
                f4v d;
#pragma unroll
                for (int rr = 0; rr < 4; ++rr)
                    d[rr] = QHf[(16 * nt + 4 * lq + rr) * 100 + 16 * mt + l15];   // Qxx[x2][x1]
                s8v Ah = *(const s8v*)(KTH + (16 * nt + l15) * 40 + 8 * lq);   // K^T rows x2
                s8v Al = *(const s8v*)(KTL + (16 * nt + l15) * 40 + 8 * lq);
                s8v Bh = *(const s8v*)(XUH + (16 * mt + l15) * 40 + 8 * lq);   // Qxu rows x1
                s8v Bl = *(const s8v*)(XUL + (16 * mt + l15) * 40 + 8 * lq);
                d = MFMA(Ah, Bh, d);
                d = MFMA(Ah, Bl, d);
                d = MFMA(Al, Bh, d);
                ushort4 hv, lv; pack4(d, &hv, &lv);
                *(ushort4*)&VBH[(16 * mt + l15) * 72 + 16 * nt + 4 * lq] = hv;
                *(ushort4*)&VBL[(16 * mt + l15) * 72 + 16 * nt + 4 * lq] = lv;
            }
            // vn[r] = qh[r] + sum_j Qxu[r][j]*k[j]; 8 lanes per row
            {
                int r = 8 * wv + (ln >> 3), kq = ln & 7;
                float acc = 0.0f;
#pragma unroll
                for (int e = 0; e < 4; ++e) {
                    int j = 4 * kq + e;
                    acc += QHf[r * 100 + 64 + j] * KVf[j];
                }
                acc += __shfl_xor(acc, 1);
                acc += __shfl_xor(acc, 2);
                acc += __shfl_xor(acc, 4);
                if (kq == 0) VVf[r] = acc + QHf[r * 100 + 96];
            }
        }
        __syncthreads();   // Bend: V, v ready for next step
    }

    // ================= forward rollout (as R9) =================
    float* sm = (float*)smb;
    {
        const size_t bt0 = (size_t)b * TT;
#pragma unroll
        for (int it = 0; it < 3; ++it) {
            int q = tid + 512 * it, row = q / 24, g = q % 24;
            const float* src = (g < 16) ? (A + (bt0 * 64 + row) * 64 + 4 * g)
                                        : (B + (bt0 * 64 + row) * 32 + 4 * (g - 16));
            *(float4*)&sm[AB0 + row * 100 + 4 * g] = *(const float4*)src;
        }
#pragma unroll
        for (int i = 0; i < 5; ++i) {
            int idx = tid + 512 * i;
            if (idx < 2080) {
                int j = idx / 65, c = idx - 65 * j;
                sm[KF0 + j * 68 + c] = wsK[bt0 * WSK_STRIDE + idx];
            }
        }
        if (tid < 64) sm[XB0 + tid] = xinit[b * 64 + tid];
    }
    __syncthreads();

    for (int t = 0; t < TT; ++t) {
        const size_t bt  = (size_t)b * TT + t;
        const size_t btn = (size_t)b * TT + ((t < TT - 1) ? (t + 1) : t);
        const int cur = t & 1;
        const int abC = cur ? AB1 : AB0, abN = cur ? AB0 : AB1;
        const int kfC = cur ? KF1 : KF0, kfN = cur ? KF0 : KF1;
        const int xbC = cur ? XB1 : XB0, xbN = cur ? XB0 : XB1;

        float4 abpre[6];
        float kpre[9];
        float cpre = 0.0f;
        if (tid >= 256) {
            const int t2 = tid - 256;
#pragma unroll
            for (int it = 0; it < 6; ++it) {
                int q = t2 + 256 * it, row = q / 24, g = q % 24;
                const float* src = (g < 16) ? (A + (btn * 64 + row) * 64 + 4 * g)
                                            : (B + (btn * 64 + row) * 32 + 4 * (g - 16));
                abpre[it] = *(const float4*)src;
            }
#pragma unroll
            for (int i = 0; i < 9; ++i) {
                int idx = t2 + 256 * i;
                kpre[i] = (idx < 2080) ? wsK[btn * WSK_STRIDE + idx] : 0.0f;
            }
            cpre = c1[bt * 64 + ((tid - 256) >> 2)];
        }

        if (tid < 256) {
            const int j = tid >> 3, q = tid & 7;
            float4 k0 = *(const float4*)&sm[kfC + j * 68 + 8 * q];
            float4 k1 = *(const float4*)&sm[kfC + j * 68 + 8 * q + 4];
            float4 x0 = *(const float4*)&sm[xbC + 8 * q];
            float4 x1 = *(const float4*)&sm[xbC + 8 * q + 4];
            float pa = dot4(k0, x0) + dot4(k1, x1);
            pa += __shfl_xor(pa, 1);
            pa += __shfl_xor(pa, 2);
            pa += __shfl_xor(pa, 4);
            if (q == 0) {
                float u = pa + sm[kfC + j * 68 + 64];
                sm[UBO + j] = u;
                out[bt * 96 + 64 + j] = u;
            }
        } else {
            const int r = (tid - 256) >> 2, q = tid & 3;
            float pa = 0.0f;
#pragma unroll
            for (int e4 = 0; e4 < 4; ++e4) {
                float4 av = *(const float4*)&sm[abC + r * 100 + 16 * q + 4 * e4];
                float4 xv = *(const float4*)&sm[xbC + 16 * q + 4 * e4];
                pa += dot4(av, xv);
            }
            pa += __shfl_xor(pa, 1);
            pa += __shfl_xor(pa, 2);
            if (q == 0) sm[AXO + r] = pa + cpre;
            if (q == 1) out[bt * 96 + r] = sm[xbC + r];
        }
        __syncthreads();

        if (tid < 256) {
            const int r = tid >> 2, q = tid & 3;
            float4 b0 = *(const float4*)&sm[abC + r * 100 + 64 + 8 * q];
            float4 b1 = *(const float4*)&sm[abC + r * 100 + 64 + 8 * q + 4];
            float4 u0 = *(const float4*)&sm[UBO + 8 * q];
            float4 u1 = *(const float4*)&sm[UBO + 8 * q + 4];
            float pa = dot4(b0, u0) + dot4(b1, u1);
            pa += __shfl_xor(pa, 1);
            pa += __shfl_xor(pa, 2);
            if (q == 0) sm[xbN + r] = sm[AXO + r] + pa;
        } else {
            const int t2 = tid - 256;
#pragma unroll
            for (int it = 0; it < 6; ++it) {
                int q = t2 + 256 * it, row = q / 24, g = q % 24;
                *(float4*)&sm[abN + row * 100 + 4 * g] = abpre[it];
            }
#pragma unroll
            for (int i = 0; i < 9; ++i) {
                int idx = t2 + 256 * i;
                if (idx < 2080) {
                    int j = idx / 65, c = idx - 65 * j;
                    sm[kfN + j * 68 + c] = kpre[i];
                }
            }
        }
        __syncthreads();
    }
}

extern "C" void kernel_launch(void* const* d_in, const int* in_sizes, int n_in,
                              void* d_out, int out_size, void* d_ws, size_t ws_size,
                              hipStream_t stream) {
    (void)in_sizes; (void)n_in; (void)out_size;
    const float* Q  = (const float*)d_in[0];
    const float* p  = (const float*)d_in[1];
    const float* A  = (const float*)d_in[2];
    const float* B  = (const float*)d_in[3];
    const float* c1 = (const float*)d_in[4];
    const float* xi = (const float*)d_in[5];
    if (ws_size < (size_t)NB * TT * WSK_STRIDE * sizeof(float)) return;
    lqr_kernel<<<NB, 512, 0, stream>>>(Q, p, A, B, c1, xi, (float*)d_out, (float*)d_ws);
}

// Round 12
// 8339.115 us; speedup vs baseline: 1.4152x; 1.0500x over previous
//
#include <hip/hip_runtime.h>
#include <math.h>

#define TT 512
#define NB 16

// ---------------- LDS byte offsets (backward) ----------------
#define QH_B   0        // QH  [96][100] f32 (col 96 = qh)
#define LI_B   38400    // LI  [32][36]  f32
#define T1_B   43008    // T1T [65][36]  f32  (row 64 = qu-solve)
#define VBH_B  52368    // Vbf-hi [64][72] us
#define VBL_B  61584    // Vbf-lo
#define FTH_B  70800    // FTbf-hi [96][72] us   FT[c][k] = F[k][c]
#define FTL_B  84624
#define WTH_B  98448    // WTbf-hi [96][72] us   WT[c][i] = W[i][c]
#define WTL_B  112272
#define T1PH_B 126096   // T1 bf16 +hi [64][40] us  (col c, rows r)
#define T1PL_B 131216   // T1 bf16 +lo
#define T1MH_B 136336   // T1 bf16 -hi [64][40] us
#define T1ML_B 141456   // T1 bf16 -lo
#define QHF_B  146576   // qhF [96] f32
#define VV_B   146960   // v [64] f32
#define CV_B   147216   // c [64] f32
#define SMB    147600

// ---------------- forward overlay (float offsets) ----------------
#define AB0 0
#define AB1 6400
#define KF0 12800
#define KF1 14976
#define XB0 17152
#define XB1 17216
#define UBO 17280
#define AXO 17312

#define WSK_STRIDE 2080   // per (b,t): rows j: [j*65 + c], col 64 = k

typedef __attribute__((ext_vector_type(8))) short s8v;
typedef __attribute__((ext_vector_type(4))) float f4v;

__device__ __forceinline__ float lanebc(float x, int lane) {
    return __int_as_float(__builtin_amdgcn_readlane(__float_as_int(x), lane));
}
__device__ __forceinline__ float dot4(float4 a, float4 b) {
    return a.x * b.x + a.y * b.y + a.z * b.z + a.w * b.w;
}
__device__ __forceinline__ unsigned short f2bf(float x) {
    unsigned int u = __float_as_uint(x);
    u += 0x7FFFu + ((u >> 16) & 1u);           // RNE
    return (unsigned short)(u >> 16);
}
__device__ __forceinline__ float bf2f(unsigned short h) {
    return __uint_as_float(((unsigned int)h) << 16);
}
// split f4v into bf16 hi + residual-lo, as two ushort4
__device__ __forceinline__ void pack4(const f4v d, ushort4* hp, ushort4* lp) {
    unsigned short h0 = f2bf(d[0]), h1 = f2bf(d[1]), h2 = f2bf(d[2]), h3 = f2bf(d[3]);
    *hp = make_ushort4(h0, h1, h2, h3);
    *lp = make_ushort4(f2bf(d[0] - bf2f(h0)), f2bf(d[1] - bf2f(h1)),
                       f2bf(d[2] - bf2f(h2)), f2bf(d[3] - bf2f(h3)));
}
// lower-triangular 16x16 tile enumeration: T=0..20 -> (mt,nt), nt<=mt
__device__ __forceinline__ void tileMN(int T, int& mt, int& nt) {
    mt = (T >= 15) ? 5 : (T >= 10) ? 4 : (T >= 6) ? 3 : (T >= 3) ? 2 : (T >= 1) ? 1 : 0;
    nt = T - mt * (mt + 1) / 2;
}
#define MFMA(a,b,c) __builtin_amdgcn_mfma_f32_16x16x32_bf16((a),(b),(c),0,0,0)

__launch_bounds__(512, 2)
__global__ void lqr_kernel(const float* __restrict__ Q, const float* __restrict__ P,
                           const float* __restrict__ A, const float* __restrict__ B,
                           const float* __restrict__ c1, const float* __restrict__ xinit,
                           float* __restrict__ out, float* __restrict__ ws)
{
    __shared__ __align__(16) unsigned char smb[SMB];
    float*          QHf = (float*)(smb + QH_B);
    float*          LIf = (float*)(smb + LI_B);
    float*          T1f = (float*)(smb + T1_B);
    unsigned short* VBH = (unsigned short*)(smb + VBH_B);
    unsigned short* VBL = (unsigned short*)(smb + VBL_B);
    unsigned short* FTH = (unsigned short*)(smb + FTH_B);
    unsigned short* FTL = (unsigned short*)(smb + FTL_B);
    unsigned short* WTH = (unsigned short*)(smb + WTH_B);
    unsigned short* WTL = (unsigned short*)(smb + WTL_B);
    unsigned short* T1PH = (unsigned short*)(smb + T1PH_B);
    unsigned short* T1PL = (unsigned short*)(smb + T1PL_B);
    unsigned short* T1MH = (unsigned short*)(smb + T1MH_B);
    unsigned short* T1ML = (unsigned short*)(smb + T1ML_B);
    float*          QHF = (float*)(smb + QHF_B);
    float*          VVf = (float*)(smb + VV_B);
    float*          CVf = (float*)(smb + CV_B);

    const int tid = threadIdx.x;
    const int b   = blockIdx.x;
    const int wv  = tid >> 6;   // 0..7
    const int ln  = tid & 63;
    const int l15 = ln & 15;
    const int lq  = ln >> 4;
    float* wsK = ws;

    const int qcnt = (wv < 5) ? 3 : 2;      // Q lower tiles per wave: {wv, wv+8, wv+16}
    const int qr = ln >> 2, qc4 = ln & 3;   // Q-stage lane mapping

    // ---- prologue: issue Q loads for t=511 immediately ----
    float4 qreg[3];
    {
        const float* Qg = Q + ((size_t)b * TT + (TT - 1)) * 9216;
#pragma unroll
        for (int tt = 0; tt < 3; ++tt) if (tt < qcnt) {
            int T = wv + 8 * tt, mt, nt; tileMN(T, mt, nt);
            qreg[tt] = *(const float4*)&Qg[(16 * mt + qr) * 96 + 16 * nt + 4 * qc4];
        }
    }

    // ---------------- init: Vbf=0, v=0, stage FTbf for t=511 ----------------
    if (tid < 384) {
        const size_t bt = (size_t)b * TT + (TT - 1);
        const int rb = tid & 15, cb = tid >> 4;
        float4 fr[4];
#pragma unroll
        for (int r = 0; r < 4; ++r) {
            const float* src = (cb < 16) ? (A + (bt * 64 + 4 * rb + r) * 64 + 4 * cb)
                                         : (B + (bt * 64 + 4 * rb + r) * 32 + 4 * (cb - 16));
            fr[r] = *(const float4*)src;
        }
#pragma unroll
        for (int c2 = 0; c2 < 4; ++c2) {
            f4v col;
            col[0] = ((const float*)&fr[0])[c2]; col[1] = ((const float*)&fr[1])[c2];
            col[2] = ((const float*)&fr[2])[c2]; col[3] = ((const float*)&fr[3])[c2];
            ushort4 hv, lv; pack4(col, &hv, &lv);
            *(ushort4*)&FTH[(4 * cb + c2) * 72 + 4 * rb] = hv;
            *(ushort4*)&FTL[(4 * cb + c2) * 72 + 4 * rb] = lv;
        }
    } else {
        float* vb = (float*)VBH;   // zero Vbf hi+lo (4608 floats contiguous)
        for (int i = tid - 384; i < 4608; i += 128) vb[i] = 0.0f;
        if (tid >= 448) VVf[tid - 448] = 0.0f;
    }
    __syncthreads();

    // ================= backward Riccati recursion =================
    for (int t = TT - 1; t >= 0; --t) {
        const size_t bt  = (size_t)b * TT + t;
        const size_t btp = (size_t)b * TT + ((t > 0) ? (t - 1) : 0);

        // ---- P1a-start: commit prefetched Q_t tiles; issue next Q; prefetch A/B ----
#pragma unroll
        for (int tt = 0; tt < 3; ++tt) if (tt < qcnt) {
            int T = wv + 8 * tt, mt, nt; tileMN(T, mt, nt);
            *(float4*)&QHf[(16 * mt + qr) * 100 + 16 * nt + 4 * qc4] = qreg[tt];
        }
        {
            const float* Qg = Q + btp * 9216;
#pragma unroll
            for (int tt = 0; tt < 3; ++tt) if (tt < qcnt) {
                int T = wv + 8 * tt, mt, nt; tileMN(T, mt, nt);
                qreg[tt] = *(const float4*)&Qg[(16 * mt + qr) * 96 + 16 * nt + 4 * qc4];
            }
        }
        // next-step F prefetch (waves 1-6 = 384 threads; consumed at P4 staging)
        float4 fp4[4];
        if (wv >= 1 && wv <= 6) {
            const int tau = tid - 64, rb = tau & 15, cb = tau >> 4;
#pragma unroll
            for (int r = 0; r < 4; ++r) {
                const float* src = (cb < 16) ? (A + (btp * 64 + 4 * rb + r) * 64 + 4 * cb)
                                             : (B + (btp * 64 + 4 * rb + r) * 32 + 4 * (cb - 16));
                fp4[r] = *(const float4*)src;
            }
        }
        if (wv == 7 && ln < 16)
            *(float4*)&CVf[4 * ln] = *(const float4*)&c1[bt * 64 + 4 * ln];
        float pv = 0.0f;
        if (ln < 48 && (ln & 3) == 0) pv = P[bt * 96 + 12 * wv + (ln >> 2)];

        // GEMM1 tile body (operand-swapped): WT[c][i] for c-block mt (0..5), i-block nt (0..3)
        auto g1Tile = [&](int mt, int nt) {
            const unsigned short* ah = VBH + (16 * nt + l15) * 72 + 8 * lq;   // V rows i
            const unsigned short* al = VBL + (16 * nt + l15) * 72 + 8 * lq;
            const unsigned short* bh = FTH + (16 * mt + l15) * 72 + 8 * lq;   // F^T rows c
            const unsigned short* bl = FTL + (16 * mt + l15) * 72 + 8 * lq;
            f4v d = {0.0f, 0.0f, 0.0f, 0.0f};
#pragma unroll
            for (int kc = 0; kc < 2; ++kc) {
                s8v Ah = *(const s8v*)(ah + 32 * kc);
                s8v Al = *(const s8v*)(al + 32 * kc);
                s8v Bh = *(const s8v*)(bh + 32 * kc);
                s8v Bl = *(const s8v*)(bl + 32 * kc);
                d = MFMA(Ah, Bh, d);
                d = MFMA(Ah, Bl, d);
                d = MFMA(Al, Bh, d);
            }
            int wi = 16 * nt + 4 * lq, wc = 16 * mt + l15;
            ushort4 hv, lv; pack4(d, &hv, &lv);
            *(ushort4*)&WTH[wc * 72 + wi] = hv;
            *(ushort4*)&WTL[wc * 72 + wi] = lv;
        };
        // Q-hat tile body: QH = Qstage + F^T W; mirror (lower tile T). No XU pack (Schur form).
        auto qhTile = [&](int T) {
            int mt, nt; tileMN(T, mt, nt);
            int orow = 16 * mt + 4 * lq, ocol = 16 * nt + l15;
            const unsigned short* ah = FTH + (16 * mt + l15) * 72 + 8 * lq;
            const unsigned short* al = FTL + (16 * mt + l15) * 72 + 8 * lq;
            const unsigned short* bh = WTH + (16 * nt + l15) * 72 + 8 * lq;
            const unsigned short* bl = WTL + (16 * nt + l15) * 72 + 8 * lq;
            f4v d;
#pragma unroll
            for (int rr = 0; rr < 4; ++rr)
                d[rr] = QHf[(orow + rr) * 100 + ocol];    // C-init = staged Q
#pragma unroll
            for (int kc = 0; kc < 2; ++kc) {
                s8v Ah = *(const s8v*)(ah + 32 * kc);
                s8v Al = *(const s8v*)(al + 32 * kc);
                s8v Bh = *(const s8v*)(bh + 32 * kc);
                s8v Bl = *(const s8v*)(bl + 32 * kc);
                d = MFMA(Ah, Bh, d);
                d = MFMA(Ah, Bl, d);
                d = MFMA(Al, Bh, d);
            }
#pragma unroll
            for (int rr = 0; rr < 4; ++rr)
                QHf[(orow + rr) * 100 + ocol] = d[rr];
            if (mt > nt) {   // mirror to upper triangle
#pragma unroll
                for (int rr = 0; rr < 4; ++rr)
                    QHf[ocol * 100 + orow + rr] = d[rr];
            }
        };

        // ---- P1a: WT u-row tiles (8, 1/wave) + qhF = p + F^T v ----
        {
            g1Tile(4 + (wv >> 2), wv & 3);
            if (ln < 48) {
                int row = 12 * wv + (ln >> 2), kq = ln & 3;
                float acc = 0.0f;
                const unsigned short* fh = FTH + row * 72 + 16 * kq;
                const unsigned short* fl = FTL + row * 72 + 16 * kq;
                const float* vvp = VVf + 16 * kq;
#pragma unroll
                for (int k = 0; k < 16; ++k)
                    acc += (bf2f(fh[k]) + bf2f(fl[k])) * vvp[k];
                acc += __shfl_xor(acc, 1);
                acc += __shfl_xor(acc, 2);
                if ((ln & 3) == 0) QHF[row] = acc + pv;
            }
        }
        __syncthreads();   // B1a: WT-u, qhF, Q-stage ready

        // ---- P1b: wave0: 3 uu Q-hat tiles ; waves1-7: 16 WT x-row tiles ----
        if (wv == 0) {
            qhTile(14); qhTile(19); qhTile(20);
        } else {
            int g0 = wv - 1;  g1Tile(g0 >> 2, g0 & 3);
            int g1 = 6 + wv;  g1Tile(g1 >> 2, g1 & 3);
            if (wv <= 2) { int g2 = 13 + wv; g1Tile(g2 >> 2, g2 & 3); }
        }
        __syncthreads();   // B1b: Quu + full WT ready

        // ---- P2': wave0 chol (setprio) || waves1-6: 18 Q-hat tiles || wave7 qh ----
        if (wv == 0) {
            __builtin_amdgcn_s_setprio(1);
            const int i = ln & 31;
            float a[32];
#pragma unroll
            for (int j4 = 0; j4 < 8; ++j4) {
                float4 v = *(const float4*)&QHf[(64 + i) * 100 + 64 + 4 * j4];
                a[4 * j4] = v.x; a[4 * j4 + 1] = v.y; a[4 * j4 + 2] = v.z; a[4 * j4 + 3] = v.w;
            }
#pragma unroll
            for (int j = 0; j < 32; ++j) {
                float dj = lanebc(a[j], j);
                float rj = rsqrtf(dj);
                a[j] *= rj;
#pragma unroll
                for (int k = j + 1; k < 32; ++k)
                    a[k] -= a[j] * lanebc(a[j], k);
            }
            float y[32];
#pragma unroll
            for (int r = 0; r < 32; ++r) {
                float acc0 = (r == i) ? 1.0f : 0.0f, acc1 = 0.0f;
#pragma unroll
                for (int j = 0; j < r; ++j) {
                    float lrj = lanebc(a[j], r);
                    if (j & 1) acc1 -= lrj * y[j]; else acc0 -= lrj * y[j];
                }
                y[r] = (acc0 + acc1) * __builtin_amdgcn_rcpf(lanebc(a[r], r));
            }
            __builtin_amdgcn_s_setprio(0);
            if (ln < 32) {
#pragma unroll
                for (int r = 0; r < 32; ++r) LIf[r * 36 + ln] = y[r];
            }
        } else if (wv == 7) {
            // qh[j] = qhF[j] + sum_i WT[j][i] c[i]
#pragma unroll
            for (int pass = 0; pass < 2; ++pass) {
                int j = pass ? (64 + (ln & 31)) : ln;
                if (pass && ln >= 32) break;
                float acc = QHF[j];
                const unsigned short* wh = WTH + j * 72;
                const unsigned short* wl = WTL + j * 72;
#pragma unroll 4
                for (int i = 0; i < 64; ++i)
                    acc += (bf2f(wh[i]) + bf2f(wl[i])) * CVf[i];
                QHf[j * 100 + 96] = acc;
            }
        } else {
            // 18 tiles (8 ux + 10 xx), 3 per wave
            int ta, tb, tc;
            switch (wv) {
                case 1: ta = 10; tb = 15; tc = 0; break;
                case 2: ta = 11; tb = 16; tc = 1; break;
                case 3: ta = 12; tb = 17; tc = 2; break;
                case 4: ta = 13; tb = 18; tc = 3; break;
                case 5: ta = 4;  tb = 5;  tc = 6; break;
                default: ta = 7; tb = 8;  tc = 9; break;   // wv==6
            }
            qhTile(ta); qhTile(tb); qhTile(tc);
        }
        __syncthreads();   // B2': QH full, LI, qh ready

        // ---- P4: T1T = (LI @ [Qux|qu])^T + bf16 +/- packs ; waves1-6 stage next FTbf ----
        {
            const int c = tid & 63, rq = tid >> 6;
            f4v acc = {0.0f, 0.0f, 0.0f, 0.0f};
#pragma unroll
            for (int j4 = 0; j4 < 8; ++j4) {
                float4 qv = *(const float4*)&QHf[c * 100 + 64 + 4 * j4];  // Qux[j][c] via symmetry
#pragma unroll
                for (int rr = 0; rr < 4; ++rr) {
                    float4 li = *(const float4*)&LIf[(4 * rq + rr) * 36 + 4 * j4];
                    acc[rr] += dot4(li, qv);
                }
            }
            *(f4v*)&T1f[c * 36 + 4 * rq] = acc;
            // bf16 split of T1 column c rows 4rq..4rq+3, positive and negated copies
            {
                ushort4 ph, pl; pack4(acc, &ph, &pl);
                *(ushort4*)&T1PH[c * 40 + 4 * rq] = ph;
                *(ushort4*)&T1PL[c * 40 + 4 * rq] = pl;
                ushort4 mh = make_ushort4((unsigned short)(ph.x ^ 0x8000u), (unsigned short)(ph.y ^ 0x8000u),
                                          (unsigned short)(ph.z ^ 0x8000u), (unsigned short)(ph.w ^ 0x8000u));
                ushort4 ml = make_ushort4((unsigned short)(pl.x ^ 0x8000u), (unsigned short)(pl.y ^ 0x8000u),
                                          (unsigned short)(pl.z ^ 0x8000u), (unsigned short)(pl.w ^ 0x8000u));
                *(ushort4*)&T1MH[c * 40 + 4 * rq] = mh;
                *(ushort4*)&T1ML[c * 40 + 4 * rq] = ml;
            }
            if (tid < 32) {   // qu column
                float aq = 0.0f;
#pragma unroll 4
                for (int j = 0; j < 32; ++j)
                    aq += LIf[tid * 36 + j] * QHf[(64 + j) * 100 + 96];
                T1f[64 * 36 + tid] = aq;
            }
            // stage next-step FTbf (waves 1-6; nothing reads FT until next step's P1a)
            if (wv >= 1 && wv <= 6) {
                const int tau = tid - 64, rb = tau & 15, cb = tau >> 4;
#pragma unroll
                for (int c2 = 0; c2 < 4; ++c2) {
                    f4v col;
                    col[0] = ((const float*)&fp4[0])[c2]; col[1] = ((const float*)&fp4[1])[c2];
                    col[2] = ((const float*)&fp4[2])[c2]; col[3] = ((const float*)&fp4[3])[c2];
                    ushort4 hv, lv; pack4(col, &hv, &lv);
                    *(ushort4*)&FTH[(4 * cb + c2) * 72 + 4 * rb] = hv;
                    *(ushort4*)&FTL[(4 * cb + c2) * 72 + 4 * rb] = lv;
                }
            }
        }
        __syncthreads();   // B4: T1T (+packs), next-FT ready

        // ---- P5': K = -(LI^T T1) -> wsK ; kvec ; Vn = Qxx - T1^T T1 -> Vbf ; vn ----
        {
            const int c = tid & 63, jq = tid >> 6;
            f4v acc = {0.0f, 0.0f, 0.0f, 0.0f};
#pragma unroll
            for (int i4 = 0; i4 < 8; ++i4) {
                float4 tv = *(const float4*)&T1f[c * 36 + 4 * i4];
#pragma unroll
                for (int ii = 0; ii < 4; ++ii) {
                    float4 li = *(const float4*)&LIf[(4 * i4 + ii) * 36 + 4 * jq];
                    float tvi = (ii == 0) ? tv.x : (ii == 1) ? tv.y : (ii == 2) ? tv.z : tv.w;
                    acc[0] += tvi * li.x; acc[1] += tvi * li.y;
                    acc[2] += tvi * li.z; acc[3] += tvi * li.w;
                }
            }
            float* wrow = wsK + bt * WSK_STRIDE;
#pragma unroll
            for (int jj = 0; jj < 4; ++jj)
                wrow[(4 * jq + jj) * 65 + c] = -acc[jj];
            if (tid < 32) {   // kvec -> global only
                float aq = 0.0f;
#pragma unroll 4
                for (int i = 0; i < 32; ++i)
                    aq += LIf[i * 36 + tid] * T1f[64 * 36 + i];
                wsK[bt * WSK_STRIDE + tid * 65 + 64] = -aq;
            }
            // Vn = Qxx - T1^T T1 via MFMA (16 tiles, 2/wave; A = -T1, B = +T1)
#pragma unroll
            for (int tt = 0; tt < 2; ++tt) {
                int T = 2 * wv + tt, mt = T >> 2, nt = T & 3;   // mt: x1-block, nt: x2-block
                f4v d;
#pragma unroll
                for (int rr = 0; rr < 4; ++rr)
                    d[rr] = QHf[(16 * nt + 4 * lq + rr) * 100 + 16 * mt + l15];   // Qxx[x2][x1]
                s8v Ah = *(const s8v*)(T1MH + (16 * nt + l15) * 40 + 8 * lq);   // -T1 cols x2
                s8v Al = *(const s8v*)(T1ML + (16 * nt + l15) * 40 + 8 * lq);
                s8v Bh = *(const s8v*)(T1PH + (16 * mt + l15) * 40 + 8 * lq);   // +T1 cols x1
                s8v Bl = *(const s8v*)(T1PL + (16 * mt + l15) * 40 + 8 * lq);
                d = MFMA(Ah, Bh, d);
                d = MFMA(Ah, Bl, d);
                d = MFMA(Al, Bh, d);
                ushort4 hv, lv; pack4(d, &hv, &lv);
                *(ushort4*)&VBH[(16 * mt + l15) * 72 + 16 * nt + 4 * lq] = hv;
                *(ushort4*)&VBL[(16 * mt + l15) * 72 + 16 * nt + 4 * lq] = lv;
            }
            // vn[r] = qh[r] - sum_j T1[j][r] * t1q[j]; 8 lanes per row
            {
                int r = 8 * wv + (ln >> 3), kq = ln & 7;
                float4 t1r = *(const float4*)&T1f[r * 36 + 4 * kq];
                float4 t1q = *(const float4*)&T1f[64 * 36 + 4 * kq];
                float acc2 = dot4(t1r, t1q);
                acc2 += __shfl_xor(acc2, 1);
                acc2 += __shfl_xor(acc2, 2);
                acc2 += __shfl_xor(acc2, 4);
                if (kq == 0) VVf[r] = QHf[r * 100 + 96] - acc2;
            }
        }
        __syncthreads();   // Bend: V, v ready for next step
    }

    // ================= forward rollout (as R9) =================
    float* sm = (float*)smb;
    {
        const size_t bt0 = (size_t)b * TT;
#pragma unroll
        for (int it = 0; it < 3; ++it) {
            int q = tid + 512 * it, row = q / 24, g = q % 24;
            const float* src = (g < 16) ? (A + (bt0 * 64 + row) * 64 + 4 * g)
                                        : (B + (bt0 * 64 + row) * 32 + 4 * (g - 16));
            *(float4*)&sm[AB0 + row * 100 + 4 * g] = *(const float4*)src;
        }
#pragma unroll
        for (int i = 0; i < 5; ++i) {
            int idx = tid + 512 * i;
            if (idx < 2080) {
                int j = idx / 65, c = idx - 65 * j;
                sm[KF0 + j * 68 + c] = wsK[bt0 * WSK_STRIDE + idx];
            }
        }
        if (tid < 64) sm[XB0 + tid] = xinit[b * 64 + tid];
    }
    __syncthreads();

    for (int t = 0; t < TT; ++t) {
        const size_t bt  = (size_t)b * TT + t;
        const size_t btn = (size_t)b * TT + ((t < TT - 1) ? (t + 1) : t);
        const int cur = t & 1;
        const int abC = cur ? AB1 : AB0, abN = cur ? AB0 : AB1;
        const int kfC = cur ? KF1 : KF0, kfN = cur ? KF0 : KF1;
        const int xbC = cur ? XB1 : XB0, xbN = cur ? XB0 : XB1;

        float4 abpre[6];
        float kpre[9];
        float cpre = 0.0f;
        if (tid >= 256) {
            const int t2 = tid - 256;
#pragma unroll
            for (int it = 0; it < 6; ++it) {
                int q = t2 + 256 * it, row = q / 24, g = q % 24;
                const float* src = (g < 16) ? (A + (btn * 64 + row) * 64 + 4 * g)
                                            : (B + (btn * 64 + row) * 32 + 4 * (g - 16));
                abpre[it] = *(const float4*)src;
            }
#pragma unroll
            for (int i = 0; i < 9; ++i) {
                int idx = t2 + 256 * i;
                kpre[i] = (idx < 2080) ? wsK[btn * WSK_STRIDE + idx] : 0.0f;
            }
            cpre = c1[bt * 64 + ((tid - 256) >> 2)];
        }

        if (tid < 256) {
            const int j = tid >> 3, q = tid & 7;
            float4 k0 = *(const float4*)&sm[kfC + j * 68 + 8 * q];
            float4 k1 = *(const float4*)&sm[kfC + j * 68 + 8 * q + 4];
            float4 x0 = *(const float4*)&sm[xbC + 8 * q];
            float4 x1 = *(const float4*)&sm[xbC + 8 * q + 4];
            float pa = dot4(k0, x0) + dot4(k1, x1);
            pa += __shfl_xor(pa, 1);
            pa += __shfl_xor(pa, 2);
            pa += __shfl_xor(pa, 4);
            if (q == 0) {
                float u = pa + sm[kfC + j * 68 + 64];
                sm[UBO + j] = u;
                out[bt * 96 + 64 + j] = u;
            }
        } else {
            const int r = (tid - 256) >> 2, q = tid & 3;
            float pa = 0.0f;
#pragma unroll
            for (int e4 = 0; e4 < 4; ++e4) {
                float4 av = *(const float4*)&sm[abC + r * 100 + 16 * q + 4 * e4];
                float4 xv = *(const float4*)&sm[xbC + 16 * q + 4 * e4];
                pa += dot4(av, xv);
            }
            pa += __shfl_xor(pa, 1);
            pa += __shfl_xor(pa, 2);
            if (q == 0) sm[AXO + r] = pa + cpre;
            if (q == 1) out[bt * 96 + r] = sm[xbC + r];
        }
        __syncthreads();

        if (tid < 256) {
            const int r = tid >> 2, q = tid & 3;
            float4 b0 = *(const float4*)&sm[abC + r * 100 + 64 + 8 * q];
            float4 b1 = *(const float4*)&sm[abC + r * 100 + 64 + 8 * q + 4];
            float4 u0 = *(const float4*)&sm[UBO + 8 * q];
            float4 u1 = *(const float4*)&sm[UBO + 8 * q + 4];
            float pa = dot4(b0, u0) + dot4(b1, u1);
            pa += __shfl_xor(pa, 1);
            pa += __shfl_xor(pa, 2);
            if (q == 0) sm[xbN + r] = sm[AXO + r] + pa;
        } else {
            const int t2 = tid - 256;
#pragma unroll
            for (int it = 0; it < 6; ++it) {
                int q = t2 + 256 * it, row = q / 24, g = q % 24;
                *(float4*)&sm[abN + row * 100 + 4 * g] = abpre[it];
            }
#pragma unroll
            for (int i = 0; i < 9; ++i) {
                int idx = t2 + 256 * i;
                if (idx < 2080) {
                    int j = idx / 65, c = idx - 65 * j;
                    sm[kfN + j * 68 + c] = kpre[i];
                }
            }
        }
        __syncthreads();
    }
}

extern "C" void kernel_launch(void* const* d_in, const int* in_sizes, int n_in,
                              void* d_out, int out_size, void* d_ws, size_t ws_size,
                              hipStream_t stream) {
    (void)in_sizes; (void)n_in; (void)out_size;
    const float* Q  = (const float*)d_in[0];
    const float* p  = (const float*)d_in[1];
    const float* A  = (const float*)d_in[2];
    const float* B  = (const float*)d_in[3];
    const float* c1 = (const float*)d_in[4];
    const float* xi = (const float*)d_in[5];
    if (ws_size < (size_t)NB * TT * WSK_STRIDE * sizeof(float)) return;
    lqr_kernel<<<NB, 512, 0, stream>>>(Q, p, A, B, c1, xi, (float*)d_out, (float*)d_ws);
}